// Round 5
// baseline (1025.032 us; speedup 1.0000x reference)
//
#include <hip/hip_runtime.h>
#include <hip/hip_bf16.h>
#include <hip/hip_cooperative_groups.h>
namespace cg = cooperative_groups;

// GraphRNN, fp32 I/O (reference dtypes are float32).
// beta = (seq @ E) / rowsum(graph); agg = graph^T @ beta (per batch);
// Xpre = agg @ Wx + b; then 1024-step scan h = tanh(Xpre_m + h @ Wh).
// MFMA path: fp32 operands split into bf16 hi+lo (rel err ~2^-18).
//
// R16: two changes on top of R15 (620us scan, 778us total):
// 1) Scan step reorder: the per-step serial path was [MFMA drain, tanh,
//    ds_write, lgkm(0), barrier, ds_read latency ~120cy, MFMA issue
//    ~1180cy]. The out-store and Xpre-prefetch (global ops) were in the
//    pre-barrier tail; now they issue in the post-barrier ds_read shadow
//    (store y_prev of step s-1 at top of step s; refill c-bank (k+3)&3,
//    still >=3 steps of lookahead). Bit-identical math.
// 2) Front fusion: the 4 pre-scan kernels execute ~45-60us of work but
//    measured 158us wall -> launch gaps dominate. Fused into ONE
//    cooperative kernel (grid 512x256, grid.sync() between phases);
//    runtime fallback to 4 separate launches if cooperative launch is
//    unsupported. Phase bodies are exact ports (identical per-thread
//    arithmetic -> bit-identical outputs).

typedef unsigned short u16;
typedef unsigned int u32;
typedef __bf16 bf16_t;
typedef __bf16 bf16x8 __attribute__((ext_vector_type(8)));
typedef float f32x4 __attribute__((ext_vector_type(4)));
typedef unsigned short u16x8 __attribute__((ext_vector_type(8)));
typedef unsigned short u16x4 __attribute__((ext_vector_type(4)));

#define LDS_P 72   // LDS pitch (u16) for 64-wide tiles (GEMM kernels)
#define HP_B  288  // h LDS row pitch (u16): row1 starts at dword 144 ->
                   // banks 16.. for row1 vs 0..15 for row0 chunks

struct HiLo { u16 hi, lo; };

__device__ __forceinline__ u16 f2bf(float f) {
  bf16_t h = (bf16_t)f;  // RNE
  return __builtin_bit_cast(u16, h);
}
__device__ __forceinline__ HiLo splitf(float v) {
  bf16_t h = (bf16_t)v;
  HiLo r;
  r.hi = __builtin_bit_cast(u16, h);
  r.lo = f2bf(v - (float)h);
  return r;
}
__device__ __forceinline__ float tanh_fast(float x) {
  float ax = fabsf(x);
  float e  = __expf(-2.0f * ax);
  float t  = __fdividef(1.0f - e, 1.0f + e);
  return copysignf(t, x);
}
// Barrier with LDS-only visibility (drains lgkmcnt, not vmcnt).
__device__ __forceinline__ void sync_lds_only() {
  __asm__ volatile("s_waitcnt lgkmcnt(0)\ns_barrier" ::: "memory");
}

// ======================= phase bodies (shared) ==============================

// P0: v<768: transpose+split E/Wx/Wh. v>=768: rnorm rows (v-768)*4..+4.
__device__ __forceinline__ void prep_body(int v, int tid,
    const float* __restrict__ E, u16* __restrict__ Eth, u16* __restrict__ Etl,
    const float* __restrict__ Wx, u16* __restrict__ Wxth, u16* __restrict__ Wxtl,
    const float* __restrict__ Wh, u16* __restrict__ Whth, u16* __restrict__ Whtl,
    const float* __restrict__ graph, float* __restrict__ rnorm) {
  if (v < 768) {
    const int mat = v >> 8, u = v & 255, d = tid;
    const float* s; u16 *dh, *dl;
    if (mat == 0)      { s = E;  dh = Eth;  dl = Etl; }
    else if (mat == 1) { s = Wx; dh = Wxth; dl = Wxtl; }
    else               { s = Wh; dh = Whth; dl = Whtl; }
    HiLo r = splitf(s[d * 256 + u]);
    dh[u * 256 + d] = r.hi;
    dl[u * 256 + d] = r.lo;
  } else {
    const int wave = tid >> 6, lane = tid & 63;
    const int row = (v - 768) * 4 + wave;  // 0..8191
    const float* p = graph + (size_t)row * 1024 + lane * 16;
    float s = 0.f;
#pragma unroll
    for (int c = 0; c < 4; c++) {
      f32x4 vv = *(const f32x4*)(p + c * 4);
#pragma unroll
      for (int j = 0; j < 4; j++) s += vv[j];
    }
#pragma unroll
    for (int off = 32; off > 0; off >>= 1) s += __shfl_xor(s, off);
    if (lane == 0) rnorm[row] = 1.0f / fmaxf(s, 1e-7f);
  }
}

// P1: betaT[b][u][l] hi/lo = (seq@E)[b,l,u] * rnorm[b,l]. v in [0,512).
__device__ __forceinline__ void beta_body(int v, int t,
    const float* __restrict__ seq, const u16* __restrict__ Eth,
    const u16* __restrict__ Etl, const float* __restrict__ rnorm,
    u16* __restrict__ betaTh, u16* __restrict__ betaTl,
    u16* Ah, u16* Al, u16* Bh, u16* Bl) {
  const int wave = t >> 6, lane = t & 63, quad = lane >> 4, l16 = lane & 15;
  const int r0 = (v >> 2) * 64, n0 = (v & 3) * 64;
  f32x4 acc[4];
#pragma unroll
  for (int i = 0; i < 4; i++) acc[i] = (f32x4){0.f, 0.f, 0.f, 0.f};

  for (int kb = 0; kb < 256; kb += 64) {
#pragma unroll
    for (int cc = 0; cc < 4; cc++) {
      int c = t + cc * 256;
      int r = c >> 4, c4 = c & 15;
      f32x4 vv = *(const f32x4*)(seq + (size_t)(r0 + r) * 256 + kb + c4 * 4);
      u16x4 hi, lo;
#pragma unroll
      for (int j = 0; j < 4; j++) {
        HiLo s = splitf(vv[j]);
        hi[j] = s.hi; lo[j] = s.lo;
      }
      *(u16x4*)(Ah + r * LDS_P + c4 * 4) = hi;
      *(u16x4*)(Al + r * LDS_P + c4 * 4) = lo;
    }
#pragma unroll
    for (int cc = 0; cc < 2; cc++) {
      int c = t + cc * 256;
      int r = c >> 3, c8 = c & 7;
      *(u16x8*)(Bh + r * LDS_P + c8 * 8) =
          *(const u16x8*)(Eth + (size_t)(n0 + r) * 256 + kb + c8 * 8);
      *(u16x8*)(Bl + r * LDS_P + c8 * 8) =
          *(const u16x8*)(Etl + (size_t)(n0 + r) * 256 + kb + c8 * 8);
    }
    __syncthreads();
#pragma unroll
    for (int kk = 0; kk < 64; kk += 32) {
      bf16x8 ah = __builtin_bit_cast(bf16x8, *(const u16x8*)(Ah + (wave * 16 + l16) * LDS_P + kk + quad * 8));
      bf16x8 al = __builtin_bit_cast(bf16x8, *(const u16x8*)(Al + (wave * 16 + l16) * LDS_P + kk + quad * 8));
#pragma unroll
      for (int tN = 0; tN < 4; tN++) {
        bf16x8 bh = __builtin_bit_cast(bf16x8, *(const u16x8*)(Bh + (tN * 16 + l16) * LDS_P + kk + quad * 8));
        bf16x8 bl = __builtin_bit_cast(bf16x8, *(const u16x8*)(Bl + (tN * 16 + l16) * LDS_P + kk + quad * 8));
        acc[tN] = __builtin_amdgcn_mfma_f32_16x16x32_bf16(ah, bh, acc[tN], 0, 0, 0);
        acc[tN] = __builtin_amdgcn_mfma_f32_16x16x32_bf16(ah, bl, acc[tN], 0, 0, 0);
        acc[tN] = __builtin_amdgcn_mfma_f32_16x16x32_bf16(al, bh, acc[tN], 0, 0, 0);
      }
    }
    __syncthreads();
  }
  const int rbase = r0 + wave * 16 + quad * 4;  // b*1024 + l, 4 consecutive l
  float rn[4];
#pragma unroll
  for (int i = 0; i < 4; i++) rn[i] = rnorm[rbase + i];
  const int bI = rbase >> 10, lI = rbase & 1023;
#pragma unroll
  for (int tN = 0; tN < 4; tN++) {
    int u = n0 + tN * 16 + l16;
    u16x4 hv, lv;
#pragma unroll
    for (int i = 0; i < 4; i++) {
      HiLo s = splitf(acc[tN][i] * rn[i]);
      hv[i] = s.hi; lv[i] = s.lo;
    }
    size_t off = ((size_t)bI << 18) + (size_t)u * 1024 + lI;
    *(u16x4*)(betaTh + off) = hv;
    *(u16x4*)(betaTl + off) = lv;
  }
}

// P2: agg[b][m][u] = sum_l graph[b][l][m] * beta[b][l][u]. v in [0,512).
__device__ __forceinline__ void agg_body(int v, int t,
    const float* __restrict__ graph, const u16* __restrict__ betaTh,
    const u16* __restrict__ betaTl, float* __restrict__ agg,
    u16* Ah, u16* Al, u16* Bh, u16* Bl) {
  const int wave = t >> 6, lane = t & 63, quad = lane >> 4, l16 = lane & 15;
  const int m0 = (v & 15) * 64, n0 = ((v >> 4) & 3) * 64, b = v >> 6;
  const float* g = graph + (size_t)b * (1024 * 1024);
  const size_t bt = (size_t)b << 18;
  f32x4 acc[4];
#pragma unroll
  for (int i = 0; i < 4; i++) acc[i] = (f32x4){0.f, 0.f, 0.f, 0.f};

  for (int kb = 0; kb < 1024; kb += 64) {
#pragma unroll
    for (int cc = 0; cc < 4; cc++) {
      int c = t + cc * 256;
      int r = c >> 4, c4 = c & 15;  // r = l_local, c4 = m-chunk of 4
      f32x4 vv = *(const f32x4*)(g + (size_t)(kb + r) * 1024 + m0 + c4 * 4);
#pragma unroll
      for (int j = 0; j < 4; j++) {
        HiLo s = splitf(vv[j]);
        Ah[(c4 * 4 + j) * LDS_P + r] = s.hi;  // A[m][l] = graph[l][m]
        Al[(c4 * 4 + j) * LDS_P + r] = s.lo;
      }
    }
#pragma unroll
    for (int cc = 0; cc < 2; cc++) {
      int c = t + cc * 256;
      int r = c >> 3, c8 = c & 7;
      *(u16x8*)(Bh + r * LDS_P + c8 * 8) =
          *(const u16x8*)(betaTh + bt + (size_t)(n0 + r) * 1024 + kb + c8 * 8);
      *(u16x8*)(Bl + r * LDS_P + c8 * 8) =
          *(const u16x8*)(betaTl + bt + (size_t)(n0 + r) * 1024 + kb + c8 * 8);
    }
    __syncthreads();
#pragma unroll
    for (int kk = 0; kk < 64; kk += 32) {
      bf16x8 ah = __builtin_bit_cast(bf16x8, *(const u16x8*)(Ah + (wave * 16 + l16) * LDS_P + kk + quad * 8));
      bf16x8 al = __builtin_bit_cast(bf16x8, *(const u16x8*)(Al + (wave * 16 + l16) * LDS_P + kk + quad * 8));
#pragma unroll
      for (int tN = 0; tN < 4; tN++) {
        bf16x8 bh = __builtin_bit_cast(bf16x8, *(const u16x8*)(Bh + (tN * 16 + l16) * LDS_P + kk + quad * 8));
        bf16x8 bl = __builtin_bit_cast(bf16x8, *(const u16x8*)(Bl + (tN * 16 + l16) * LDS_P + kk + quad * 8));
        acc[tN] = __builtin_amdgcn_mfma_f32_16x16x32_bf16(ah, bh, acc[tN], 0, 0, 0);
        acc[tN] = __builtin_amdgcn_mfma_f32_16x16x32_bf16(ah, bl, acc[tN], 0, 0, 0);
        acc[tN] = __builtin_amdgcn_mfma_f32_16x16x32_bf16(al, bh, acc[tN], 0, 0, 0);
      }
    }
    __syncthreads();
  }
  const int mbase = m0 + wave * 16 + quad * 4;
#pragma unroll
  for (int tN = 0; tN < 4; tN++) {
    int u = n0 + tN * 16 + l16;
#pragma unroll
    for (int i = 0; i < 4; i++)
      agg[((size_t)b * 1024 + mbase + i) * 256 + u] = acc[tN][i];
  }
}

// P3: Xpre[m][b][u] = (agg @ Wx)[b,m,u] + bias[u]. v in [0,512).
__device__ __forceinline__ void xpre_body(int v, int t,
    const float* __restrict__ agg, const u16* __restrict__ Wxth,
    const u16* __restrict__ Wxtl, const float* __restrict__ bias,
    float* __restrict__ Xpre,
    u16* Ah, u16* Al, u16* Bh, u16* Bl) {
  const int wave = t >> 6, lane = t & 63, quad = lane >> 4, l16 = lane & 15;
  const int r0 = (v >> 2) * 64, n0 = (v & 3) * 64;
  f32x4 acc[4];
#pragma unroll
  for (int i = 0; i < 4; i++) acc[i] = (f32x4){0.f, 0.f, 0.f, 0.f};

  for (int kb = 0; kb < 256; kb += 64) {
#pragma unroll
    for (int cc = 0; cc < 4; cc++) {
      int c = t + cc * 256;
      int r = c >> 4, c4 = c & 15;
      f32x4 vv = *(const f32x4*)(agg + (size_t)(r0 + r) * 256 + kb + c4 * 4);
      u16x4 hi, lo;
#pragma unroll
      for (int j = 0; j < 4; j++) {
        HiLo s = splitf(vv[j]);
        hi[j] = s.hi; lo[j] = s.lo;
      }
      *(u16x4*)(Ah + r * LDS_P + c4 * 4) = hi;
      *(u16x4*)(Al + r * LDS_P + c4 * 4) = lo;
    }
#pragma unroll
    for (int cc = 0; cc < 2; cc++) {
      int c = t + cc * 256;
      int r = c >> 3, c8 = c & 7;
      *(u16x8*)(Bh + r * LDS_P + c8 * 8) =
          *(const u16x8*)(Wxth + (size_t)(n0 + r) * 256 + kb + c8 * 8);
      *(u16x8*)(Bl + r * LDS_P + c8 * 8) =
          *(const u16x8*)(Wxtl + (size_t)(n0 + r) * 256 + kb + c8 * 8);
    }
    __syncthreads();
#pragma unroll
    for (int kk = 0; kk < 64; kk += 32) {
      bf16x8 ah = __builtin_bit_cast(bf16x8, *(const u16x8*)(Ah + (wave * 16 + l16) * LDS_P + kk + quad * 8));
      bf16x8 al = __builtin_bit_cast(bf16x8, *(const u16x8*)(Al + (wave * 16 + l16) * LDS_P + kk + quad * 8));
#pragma unroll
      for (int tN = 0; tN < 4; tN++) {
        bf16x8 bh = __builtin_bit_cast(bf16x8, *(const u16x8*)(Bh + (tN * 16 + l16) * LDS_P + kk + quad * 8));
        bf16x8 bl = __builtin_bit_cast(bf16x8, *(const u16x8*)(Bl + (tN * 16 + l16) * LDS_P + kk + quad * 8));
        acc[tN] = __builtin_amdgcn_mfma_f32_16x16x32_bf16(ah, bh, acc[tN], 0, 0, 0);
        acc[tN] = __builtin_amdgcn_mfma_f32_16x16x32_bf16(ah, bl, acc[tN], 0, 0, 0);
        acc[tN] = __builtin_amdgcn_mfma_f32_16x16x32_bf16(al, bh, acc[tN], 0, 0, 0);
      }
    }
    __syncthreads();
  }
  const int rbase = r0 + wave * 16 + quad * 4;  // b*1024 + m
  const int bI = rbase >> 10;
#pragma unroll
  for (int tN = 0; tN < 4; tN++) {
    int u = n0 + tN * 16 + l16;
    float bu = bias[u];
#pragma unroll
    for (int i = 0; i < 4; i++) {
      int mI = (rbase + i) & 1023;
      Xpre[((size_t)mI * 8 + bI) * 256 + u] = acc[tN][i] + bu;
    }
  }
}

// ======================= standalone kernels (fallback path) =================
__global__ void k_prep(const float* E, u16* Eth, u16* Etl,
                       const float* Wx, u16* Wxth, u16* Wxtl,
                       const float* Wh, u16* Whth, u16* Whtl,
                       const float* graph, float* rnorm) {
  prep_body(blockIdx.x, threadIdx.x, E, Eth, Etl, Wx, Wxth, Wxtl, Wh, Whth, Whtl, graph, rnorm);
}
__global__ __launch_bounds__(256, 2) void k_beta(const float* seq, const u16* Eth, const u16* Etl,
                                                 const float* rnorm, u16* betaTh, u16* betaTl) {
  __shared__ u16 Ah[64 * LDS_P], Al[64 * LDS_P], Bh[64 * LDS_P], Bl[64 * LDS_P];
  beta_body(blockIdx.x, threadIdx.x, seq, Eth, Etl, rnorm, betaTh, betaTl, Ah, Al, Bh, Bl);
}
__global__ __launch_bounds__(256, 2) void k_agg(const float* graph, const u16* betaTh, const u16* betaTl,
                                                float* agg) {
  __shared__ u16 Ah[64 * LDS_P], Al[64 * LDS_P], Bh[64 * LDS_P], Bl[64 * LDS_P];
  agg_body(blockIdx.x, threadIdx.x, graph, betaTh, betaTl, agg, Ah, Al, Bh, Bl);
}
__global__ __launch_bounds__(256, 2) void k_xpre(const float* agg, const u16* Wxth, const u16* Wxtl,
                                                 const float* bias, float* Xpre) {
  __shared__ u16 Ah[64 * LDS_P], Al[64 * LDS_P], Bh[64 * LDS_P], Bl[64 * LDS_P];
  xpre_body(blockIdx.x, threadIdx.x, agg, Wxth, Wxtl, bias, Xpre, Ah, Al, Bh, Bl);
}

// ======================= fused front (cooperative) ==========================
__global__ __launch_bounds__(256, 2) void fused_front(
    const float* seq, const float* graph, const float* E, const float* Wx,
    const float* Wh, const float* bias,
    u16* Eth, u16* Etl, u16* Wxth, u16* Wxtl, u16* Whth, u16* Whtl,
    float* rnorm, u16* betaTh, u16* betaTl, float* agg, float* Xpre) {
  __shared__ u16 Ah[64 * LDS_P], Al[64 * LDS_P], Bh[64 * LDS_P], Bl[64 * LDS_P];
  cg::grid_group grid = cg::this_grid();
  const int t = threadIdx.x;
  // P0: weight splits + rowsums (2816 virtual blocks, grid-stride).
  for (int v = blockIdx.x; v < 2816; v += 512)
    prep_body(v, t, E, Eth, Etl, Wx, Wxth, Wxtl, Wh, Whth, Whtl, graph, rnorm);
  grid.sync();
  beta_body(blockIdx.x, t, seq, Eth, Etl, rnorm, betaTh, betaTl, Ah, Al, Bh, Bl);
  grid.sync();
  agg_body(blockIdx.x, t, graph, betaTh, betaTl, agg, Ah, Al, Bh, Bl);
  grid.sync();
  xpre_body(blockIdx.x, t, agg, Wxth, Wxtl, bias, Xpre, Ah, Al, Bh, Bl);
}

// ---------------- K5: sequential scan, 8 WGs (1 batch each), 8 waves --------
// Wave w owns output cols [w*32, w*32+32) = 2 n-tiles. A-tile: 2 rows
// (h_hi, h_lo), read row clamped to l16&1 -> broadcast, conflict-free.
// Quad0 consumes n-tile 0, quad1 n-tile 1 (C rows are bit-exact dups of
// rows 0/1) -> 1 tanh chain/lane. R16: out-store (y_prev) and c-bank
// refill moved to the TOP of the step, into the post-barrier ds_read
// latency shadow; bank (k+3)&3 refilled with Xpre[s+3] (>=3-step
// lookahead). Double-buffered h, running pointers. Bit-identical math.
__global__ __launch_bounds__(512, 2) void rnn_scan(const u16* __restrict__ Whth,
                                                   const u16* __restrict__ Whtl,
                                                   const float* __restrict__ Xpre,
                                                   float* __restrict__ out) {
  __shared__ u16 h2[2][2 * HP_B];
  const int b = blockIdx.x;
  const int t = threadIdx.x;
  const int w = t >> 6, lane = t & 63, quad = lane >> 4, l16 = lane & 15;
  const int colbase = w * 32;
  const bool epi = (quad < 2);           // quad0 -> tile0, quad1 -> tile1
  const int col_e = colbase + quad * 16 + l16;  // valid for epi lanes

  // Preload Wh hi+lo fragments: 2 n-tiles x 8 k-blocks, hi+lo
  bf16x8 bwh[2][8], bwl[2][8];
#pragma unroll
  for (int tN = 0; tN < 2; tN++) {
    const u16* wph = Whth + (size_t)(colbase + tN * 16 + l16) * 256 + quad * 8;
    const u16* wpl = Whtl + (size_t)(colbase + tN * 16 + l16) * 256 + quad * 8;
#pragma unroll
    for (int kb = 0; kb < 8; kb++) {
      bwh[tN][kb] = __builtin_bit_cast(bf16x8, *(const u16x8*)(wph + kb * 32));
      bwl[tN][kb] = __builtin_bit_cast(bf16x8, *(const u16x8*)(wpl + kb * 32));
    }
  }
  for (int i = t; i < 2 * 2 * HP_B; i += 512) ((u16*)h2)[i] = 0;

  // c banks 0..3: additive input for steps s..s+3 (epi lanes only).
  float cb[4];
  if (epi) {
#pragma unroll
    for (int k = 0; k < 4; k++) cb[k] = Xpre[(size_t)k * 2048 + b * 256 + col_e];
  }
  // Running pointers. ldp -> Xpre row 4 (first refill target value).
  const float* ldp = Xpre + 4 * 2048 + b * 256 + col_e;
  float* outp = out + (size_t)b * 262144 + col_e;  // next store row = 0
  float y_prev = 0.f;
  // Hoisted LDS bases. Read base: row clamped to l16&1 (broadcast dup rows).
  const u16* rb0 = &h2[0][(l16 & 1) * HP_B + quad * 8];
  const u16* rb1 = &h2[1][(l16 & 1) * HP_B + quad * 8];
  u16* wb0 = &h2[0][0];
  u16* wb1 = &h2[1][0];
  __syncthreads();

  for (int m4 = 0; m4 < 1024; m4 += 4) {
#pragma unroll
    for (int k = 0; k < 4; k++) {
      const int p = k & 1;                       // compile-time in unrolled body
      const u16* rb = p ? rb1 : rb0;
      u16* hw = p ? wb0 : wb1;                   // write the other buffer

      // Hoist all 8 A-fragment reads (one lgkmcnt ramp, MFMAs pipeline).
      bf16x8 af[8];
#pragma unroll
      for (int kb = 0; kb < 8; kb++)
        af[kb] = __builtin_bit_cast(bf16x8, *(const u16x8*)(rb + kb * 32));

      // Global ops in the ds_read latency shadow: store previous step's
      // output; refill c-bank (k+3)&3 with Xpre[s+3] (s = m4+k).
      if (epi) {
        if (m4 + k > 0) { *outp = y_prev; outp += 256; }
        if (m4 + k >= 1 && m4 + k <= 1020) { cb[(k + 3) & 3] = *ldp; ldp += 2048; }
      }

      f32x4 a0a = {0.f,0.f,0.f,0.f}, a0b = {0.f,0.f,0.f,0.f};
      f32x4 a1a = {0.f,0.f,0.f,0.f}, a1b = {0.f,0.f,0.f,0.f};
#pragma unroll
      for (int kb = 0; kb < 4; kb++) {
        a0a = __builtin_amdgcn_mfma_f32_16x16x32_bf16(af[kb], bwh[0][kb], a0a, 0, 0, 0);
        a1a = __builtin_amdgcn_mfma_f32_16x16x32_bf16(af[kb], bwh[1][kb], a1a, 0, 0, 0);
        a0b = __builtin_amdgcn_mfma_f32_16x16x32_bf16(af[kb + 4], bwh[0][kb + 4], a0b, 0, 0, 0);
        a1b = __builtin_amdgcn_mfma_f32_16x16x32_bf16(af[kb + 4], bwh[1][kb + 4], a1b, 0, 0, 0);
        a0a = __builtin_amdgcn_mfma_f32_16x16x32_bf16(af[kb], bwl[0][kb], a0a, 0, 0, 0);
        a1a = __builtin_amdgcn_mfma_f32_16x16x32_bf16(af[kb], bwl[1][kb], a1a, 0, 0, 0);
        a0b = __builtin_amdgcn_mfma_f32_16x16x32_bf16(af[kb + 4], bwl[0][kb + 4], a0b, 0, 0, 0);
        a1b = __builtin_amdgcn_mfma_f32_16x16x32_bf16(af[kb + 4], bwl[1][kb + 4], a1b, 0, 0, 0);
      }

      // Epilogue distributed: quad0 uses (a0a,a0b), quad1 uses (a1a,a1b).
      // Same recombine order as R15: (hi_part + lo_part) + c.
      if (epi) {
        float sA0 = quad ? a1a[0] : a0a[0];
        float sA1 = quad ? a1a[1] : a0a[1];
        float sB0 = quad ? a1b[0] : a0b[0];
        float sB1 = quad ? a1b[1] : a0b[1];
        float hi_part = sA0 + sB0;
        float lo_part = sA1 + sB1;
        float x = (hi_part + lo_part) + cb[k];
        float y = tanh_fast(x);
        HiLo s = splitf(y);
        hw[col_e] = s.hi;           // row 0 = h_hi
        hw[HP_B + col_e] = s.lo;    // row 1 = h_lo
        y_prev = y;                 // stored at top of next step
      }
      sync_lds_only();
    }
  }
  if (epi) *outp = y_prev;          // final step's output (row 1023)
}

extern "C" void kernel_launch(void* const* d_in, const int* in_sizes, int n_in,
                              void* d_out, int out_size, void* d_ws, size_t ws_size,
                              hipStream_t stream) {
  (void)in_sizes; (void)n_in; (void)out_size; (void)ws_size;
  const float* seq   = (const float*)d_in[0];  // (8,1024,256) f32
  const float* graph = (const float*)d_in[1];  // (8,1024,1024) f32
  const float* E     = (const float*)d_in[2];  // (256,256) f32
  const float* Wx    = (const float*)d_in[3];  // (256,256) f32
  const float* Wh    = (const float*)d_in[4];  // (256,256) f32
  const float* bias  = (const float*)d_in[5];  // (256,) f32
  float* out = (float*)d_out;                  // (8,1024,256) f32

  // workspace layout (bytes): ~26 MB total
  char* w = (char*)d_ws;
  float* rnorm  = (float*)(w + 0);          //  32 KB
  u16*   Eth    = (u16*)(w + 32768);        // 128 KB
  u16*   Etl    = (u16*)(w + 163840);
  u16*   Wxth   = (u16*)(w + 294912);
  u16*   Wxtl   = (u16*)(w + 425984);
  u16*   Whth   = (u16*)(w + 557056);
  u16*   Whtl   = (u16*)(w + 688128);
  u16*   betaTh = (u16*)(w + 819200);       // 4 MB [b][u][l]
  u16*   betaTl = (u16*)(w + 5013504);      // 4 MB
  float* agg    = (float*)(w + 9207808);    // 8 MB [b][m][u]
  float* Xpre   = (float*)(w + 17596416);   // 8 MB [m][b][u]

  void* args[] = {&seq, &graph, &E, &Wx, &Wh, &bias,
                  &Eth, &Etl, &Wxth, &Wxtl, &Whth, &Whtl,
                  &rnorm, &betaTh, &betaTl, &agg, &Xpre};
  hipError_t ce = hipLaunchCooperativeKernel((void*)fused_front, dim3(512), dim3(256),
                                             args, 0, stream);
  if (ce != hipSuccess) {
    // Fallback: sequential launches (identical math).
    k_prep<<<2816, 256, 0, stream>>>(E, Eth, Etl, Wx, Wxth, Wxtl, Wh, Whth, Whtl, graph, rnorm);
    k_beta<<<512, 256, 0, stream>>>(seq, Eth, Etl, rnorm, betaTh, betaTl);
    k_agg<<<512, 256, 0, stream>>>(graph, betaTh, betaTl, agg);
    k_xpre<<<512, 256, 0, stream>>>(agg, Wxth, Wxtl, bias, Xpre);
  }
  rnn_scan<<<dim3(8), 512, 0, stream>>>(Whth, Whtl, Xpre, out);
}

// Round 6
// 990.959 us; speedup vs baseline: 1.0344x; 1.0344x over previous
//
#include <hip/hip_runtime.h>
#include <hip/hip_bf16.h>

// GraphRNN, fp32 I/O (reference dtypes are float32).
// beta = (seq @ E) / rowsum(graph); agg = graph^T @ beta (per batch);
// Xpre = agg @ Wx + b; then 1024-step scan h = tanh(Xpre_m + h @ Wh).
// MFMA path: fp32 operands split into bf16 hi+lo (rel err ~2^-18).
//
// R17 = R15 revert + quad-split scan epilogue. R16 post-mortem: (a) coop
// front grid.sync x3 cost +204us vs 4 separate launches -> reverted;
// (b) putting out-store/prefetch BEFORE the MFMA block added serial time
// ahead of MFMA issue (+43us) -> reverted. New in R17: the step's MFMA
// stream is split into [a1-group 16 MFMAs][quad1 epilogue][a0-group 16
// MFMAs][quad0 epilogue][barrier]. Each quad's epilogue depends only on
// its own accumulators, so quad1's tanh/splitf/ds_writes (VALU+LDS pipes)
// overlap the a0 MFMA group (matrix pipe). Per-accumulator MFMA order and
// per-lane arithmetic unchanged -> bit-identical to R15. Also: beta grid
// (4,128) so same-r0 blocks are dispatch-adjacent (L2 reuse of seq).

typedef unsigned short u16;
typedef unsigned int u32;
typedef __bf16 bf16_t;
typedef __bf16 bf16x8 __attribute__((ext_vector_type(8)));
typedef float f32x4 __attribute__((ext_vector_type(4)));
typedef unsigned short u16x8 __attribute__((ext_vector_type(8)));
typedef unsigned short u16x4 __attribute__((ext_vector_type(4)));

#define LDS_P 72   // LDS pitch (u16) for 64-wide tiles (GEMM kernels)
#define HP_B  288  // h LDS row pitch (u16): row1 starts at dword 144 ->
                   // banks 16.. for row1 vs 0..15 for row0 chunks

struct HiLo { u16 hi, lo; };

__device__ __forceinline__ u16 f2bf(float f) {
  bf16_t h = (bf16_t)f;  // RNE
  return __builtin_bit_cast(u16, h);
}
__device__ __forceinline__ HiLo splitf(float v) {
  bf16_t h = (bf16_t)v;
  HiLo r;
  r.hi = __builtin_bit_cast(u16, h);
  r.lo = f2bf(v - (float)h);
  return r;
}
__device__ __forceinline__ float tanh_fast(float x) {
  float ax = fabsf(x);
  float e  = __expf(-2.0f * ax);
  float t  = __fdividef(1.0f - e, 1.0f + e);
  return copysignf(t, x);
}
// Barrier with LDS-only visibility (drains lgkmcnt, not vmcnt).
__device__ __forceinline__ void sync_lds_only() {
  __asm__ volatile("s_waitcnt lgkmcnt(0)\ns_barrier" ::: "memory");
}

// ---------------- K0+K1 fused: weight transpose/split + graph row-sums -----
// bid < 768: transpose+split E/Wx/Wh (mat = bid>>8, u = bid&255).
// bid >= 768: rnorm[b,l] = 1 / max(sum_m graph[b,l,m], 1e-7), 4 rows/block.
__global__ void prep_split_rowsum(const float* __restrict__ E, u16* __restrict__ Eth, u16* __restrict__ Etl,
                                  const float* __restrict__ Wx, u16* __restrict__ Wxth, u16* __restrict__ Wxtl,
                                  const float* __restrict__ Wh, u16* __restrict__ Whth, u16* __restrict__ Whtl,
                                  const float* __restrict__ graph, float* __restrict__ rnorm) {
  const int bid = blockIdx.x;
  if (bid < 768) {
    const int mat = bid >> 8, u = bid & 255, d = threadIdx.x;
    const float* s; u16 *dh, *dl;
    if (mat == 0)      { s = E;  dh = Eth;  dl = Etl; }
    else if (mat == 1) { s = Wx; dh = Wxth; dl = Wxtl; }
    else               { s = Wh; dh = Whth; dl = Whtl; }
    HiLo r = splitf(s[d * 256 + u]);
    dh[u * 256 + d] = r.hi;
    dl[u * 256 + d] = r.lo;
  } else {
    const int wave = threadIdx.x >> 6, lane = threadIdx.x & 63;
    const int row = (bid - 768) * 4 + wave;  // 0..8191
    const float* p = graph + (size_t)row * 1024 + lane * 16;
    float s = 0.f;
#pragma unroll
    for (int c = 0; c < 4; c++) {
      f32x4 v = *(const f32x4*)(p + c * 4);
#pragma unroll
      for (int j = 0; j < 4; j++) s += v[j];
    }
#pragma unroll
    for (int off = 32; off > 0; off >>= 1) s += __shfl_xor(s, off);
    if (lane == 0) rnorm[row] = 1.0f / fmaxf(s, 1e-7f);
  }
}

// ---------------- K2: betaT[b][u][l] hi/lo = (seq@E)[b,l,u] * rnorm[b,l] ----
// Grid (4,128): x = n0-tile, y = r0-tile, so the 4 blocks sharing an r0
// row-panel are dispatch-adjacent (seq tile L2 reuse).
__global__ __launch_bounds__(256, 2) void gemm_beta(const float* __restrict__ seq,
                                                    const u16* __restrict__ Eth,
                                                    const u16* __restrict__ Etl,
                                                    const float* __restrict__ rnorm,
                                                    u16* __restrict__ betaTh,
                                                    u16* __restrict__ betaTl) {
  __shared__ u16 Ah[64 * LDS_P], Al[64 * LDS_P];
  __shared__ u16 Bh[64 * LDS_P], Bl[64 * LDS_P];
  const int t = threadIdx.x;
  const int wave = t >> 6, lane = t & 63, quad = lane >> 4, l16 = lane & 15;
  const int r0 = blockIdx.y * 64, n0 = blockIdx.x * 64;
  f32x4 acc[4];
#pragma unroll
  for (int i = 0; i < 4; i++) acc[i] = (f32x4){0.f, 0.f, 0.f, 0.f};

  for (int kb = 0; kb < 256; kb += 64) {
#pragma unroll
    for (int cc = 0; cc < 4; cc++) {
      int c = t + cc * 256;
      int r = c >> 4, c4 = c & 15;
      f32x4 v = *(const f32x4*)(seq + (size_t)(r0 + r) * 256 + kb + c4 * 4);
      u16x4 hi, lo;
#pragma unroll
      for (int j = 0; j < 4; j++) {
        HiLo s = splitf(v[j]);
        hi[j] = s.hi; lo[j] = s.lo;
      }
      *(u16x4*)(Ah + r * LDS_P + c4 * 4) = hi;
      *(u16x4*)(Al + r * LDS_P + c4 * 4) = lo;
    }
#pragma unroll
    for (int cc = 0; cc < 2; cc++) {
      int c = t + cc * 256;
      int r = c >> 3, c8 = c & 7;
      *(u16x8*)(Bh + r * LDS_P + c8 * 8) =
          *(const u16x8*)(Eth + (size_t)(n0 + r) * 256 + kb + c8 * 8);
      *(u16x8*)(Bl + r * LDS_P + c8 * 8) =
          *(const u16x8*)(Etl + (size_t)(n0 + r) * 256 + kb + c8 * 8);
    }
    __syncthreads();
#pragma unroll
    for (int kk = 0; kk < 64; kk += 32) {
      bf16x8 ah = __builtin_bit_cast(bf16x8, *(const u16x8*)(Ah + (wave * 16 + l16) * LDS_P + kk + quad * 8));
      bf16x8 al = __builtin_bit_cast(bf16x8, *(const u16x8*)(Al + (wave * 16 + l16) * LDS_P + kk + quad * 8));
#pragma unroll
      for (int tN = 0; tN < 4; tN++) {
        bf16x8 bh = __builtin_bit_cast(bf16x8, *(const u16x8*)(Bh + (tN * 16 + l16) * LDS_P + kk + quad * 8));
        bf16x8 bl = __builtin_bit_cast(bf16x8, *(const u16x8*)(Bl + (tN * 16 + l16) * LDS_P + kk + quad * 8));
        acc[tN] = __builtin_amdgcn_mfma_f32_16x16x32_bf16(ah, bh, acc[tN], 0, 0, 0);
        acc[tN] = __builtin_amdgcn_mfma_f32_16x16x32_bf16(ah, bl, acc[tN], 0, 0, 0);
        acc[tN] = __builtin_amdgcn_mfma_f32_16x16x32_bf16(al, bh, acc[tN], 0, 0, 0);
      }
    }
    __syncthreads();
  }
  const int rbase = r0 + wave * 16 + quad * 4;  // b*1024 + l, 4 consecutive l
  float rn[4];
#pragma unroll
  for (int i = 0; i < 4; i++) rn[i] = rnorm[rbase + i];
  const int bI = rbase >> 10, lI = rbase & 1023;
#pragma unroll
  for (int tN = 0; tN < 4; tN++) {
    int u = n0 + tN * 16 + l16;
    u16x4 hv, lv;
#pragma unroll
    for (int i = 0; i < 4; i++) {
      HiLo s = splitf(acc[tN][i] * rn[i]);
      hv[i] = s.hi; lv[i] = s.lo;
    }
    size_t off = ((size_t)bI << 18) + (size_t)u * 1024 + lI;
    *(u16x4*)(betaTh + off) = hv;
    *(u16x4*)(betaTl + off) = lv;
  }
}

// ---------------- K3: agg[b][m][u] = sum_l graph[b][l][m] * beta[b][l][u] ---
__global__ __launch_bounds__(256, 2) void gemm_agg(const float* __restrict__ graph,
                                                   const u16* __restrict__ betaTh,
                                                   const u16* __restrict__ betaTl,
                                                   float* __restrict__ agg) {
  __shared__ u16 Ah[64 * LDS_P], Al[64 * LDS_P];
  __shared__ u16 Bh[64 * LDS_P], Bl[64 * LDS_P];
  const int t = threadIdx.x;
  const int wave = t >> 6, lane = t & 63, quad = lane >> 4, l16 = lane & 15;
  const int m0 = blockIdx.x * 64, n0 = blockIdx.y * 64, b = blockIdx.z;
  const float* g = graph + (size_t)b * (1024 * 1024);
  const size_t bt = (size_t)b << 18;
  f32x4 acc[4];
#pragma unroll
  for (int i = 0; i < 4; i++) acc[i] = (f32x4){0.f, 0.f, 0.f, 0.f};

  for (int kb = 0; kb < 1024; kb += 64) {
#pragma unroll
    for (int cc = 0; cc < 4; cc++) {
      int c = t + cc * 256;
      int r = c >> 4, c4 = c & 15;  // r = l_local, c4 = m-chunk of 4
      f32x4 v = *(const f32x4*)(g + (size_t)(kb + r) * 1024 + m0 + c4 * 4);
#pragma unroll
      for (int j = 0; j < 4; j++) {
        HiLo s = splitf(v[j]);
        Ah[(c4 * 4 + j) * LDS_P + r] = s.hi;  // A[m][l] = graph[l][m]
        Al[(c4 * 4 + j) * LDS_P + r] = s.lo;
      }
    }
#pragma unroll
    for (int cc = 0; cc < 2; cc++) {
      int c = t + cc * 256;
      int r = c >> 3, c8 = c & 7;
      *(u16x8*)(Bh + r * LDS_P + c8 * 8) =
          *(const u16x8*)(betaTh + bt + (size_t)(n0 + r) * 1024 + kb + c8 * 8);
      *(u16x8*)(Bl + r * LDS_P + c8 * 8) =
          *(const u16x8*)(betaTl + bt + (size_t)(n0 + r) * 1024 + kb + c8 * 8);
    }
    __syncthreads();
#pragma unroll
    for (int kk = 0; kk < 64; kk += 32) {
      bf16x8 ah = __builtin_bit_cast(bf16x8, *(const u16x8*)(Ah + (wave * 16 + l16) * LDS_P + kk + quad * 8));
      bf16x8 al = __builtin_bit_cast(bf16x8, *(const u16x8*)(Al + (wave * 16 + l16) * LDS_P + kk + quad * 8));
#pragma unroll
      for (int tN = 0; tN < 4; tN++) {
        bf16x8 bh = __builtin_bit_cast(bf16x8, *(const u16x8*)(Bh + (tN * 16 + l16) * LDS_P + kk + quad * 8));
        bf16x8 bl = __builtin_bit_cast(bf16x8, *(const u16x8*)(Bl + (tN * 16 + l16) * LDS_P + kk + quad * 8));
        acc[tN] = __builtin_amdgcn_mfma_f32_16x16x32_bf16(ah, bh, acc[tN], 0, 0, 0);
        acc[tN] = __builtin_amdgcn_mfma_f32_16x16x32_bf16(ah, bl, acc[tN], 0, 0, 0);
        acc[tN] = __builtin_amdgcn_mfma_f32_16x16x32_bf16(al, bh, acc[tN], 0, 0, 0);
      }
    }
    __syncthreads();
  }
  const int mbase = m0 + wave * 16 + quad * 4;
#pragma unroll
  for (int tN = 0; tN < 4; tN++) {
    int u = n0 + tN * 16 + l16;
#pragma unroll
    for (int i = 0; i < 4; i++)
      agg[((size_t)b * 1024 + mbase + i) * 256 + u] = acc[tN][i];
  }
}

// ---------------- K4: Xpre[m][b][u] = (agg @ Wx)[b,m,u] + bias[u] (fp32) ----
__global__ __launch_bounds__(256, 2) void gemm_xpre(const float* __restrict__ agg,
                                                    const u16* __restrict__ Wxth,
                                                    const u16* __restrict__ Wxtl,
                                                    const float* __restrict__ bias,
                                                    float* __restrict__ Xpre) {
  __shared__ u16 Ah[64 * LDS_P], Al[64 * LDS_P];
  __shared__ u16 Bh[64 * LDS_P], Bl[64 * LDS_P];
  const int t = threadIdx.x;
  const int wave = t >> 6, lane = t & 63, quad = lane >> 4, l16 = lane & 15;
  const int r0 = blockIdx.x * 64, n0 = blockIdx.y * 64;
  f32x4 acc[4];
#pragma unroll
  for (int i = 0; i < 4; i++) acc[i] = (f32x4){0.f, 0.f, 0.f, 0.f};

  for (int kb = 0; kb < 256; kb += 64) {
#pragma unroll
    for (int cc = 0; cc < 4; cc++) {
      int c = t + cc * 256;
      int r = c >> 4, c4 = c & 15;
      f32x4 v = *(const f32x4*)(agg + (size_t)(r0 + r) * 256 + kb + c4 * 4);
      u16x4 hi, lo;
#pragma unroll
      for (int j = 0; j < 4; j++) {
        HiLo s = splitf(v[j]);
        hi[j] = s.hi; lo[j] = s.lo;
      }
      *(u16x4*)(Ah + r * LDS_P + c4 * 4) = hi;
      *(u16x4*)(Al + r * LDS_P + c4 * 4) = lo;
    }
#pragma unroll
    for (int cc = 0; cc < 2; cc++) {
      int c = t + cc * 256;
      int r = c >> 3, c8 = c & 7;
      *(u16x8*)(Bh + r * LDS_P + c8 * 8) =
          *(const u16x8*)(Wxth + (size_t)(n0 + r) * 256 + kb + c8 * 8);
      *(u16x8*)(Bl + r * LDS_P + c8 * 8) =
          *(const u16x8*)(Wxtl + (size_t)(n0 + r) * 256 + kb + c8 * 8);
    }
    __syncthreads();
#pragma unroll
    for (int kk = 0; kk < 64; kk += 32) {
      bf16x8 ah = __builtin_bit_cast(bf16x8, *(const u16x8*)(Ah + (wave * 16 + l16) * LDS_P + kk + quad * 8));
      bf16x8 al = __builtin_bit_cast(bf16x8, *(const u16x8*)(Al + (wave * 16 + l16) * LDS_P + kk + quad * 8));
#pragma unroll
      for (int tN = 0; tN < 4; tN++) {
        bf16x8 bh = __builtin_bit_cast(bf16x8, *(const u16x8*)(Bh + (tN * 16 + l16) * LDS_P + kk + quad * 8));
        bf16x8 bl = __builtin_bit_cast(bf16x8, *(const u16x8*)(Bl + (tN * 16 + l16) * LDS_P + kk + quad * 8));
        acc[tN] = __builtin_amdgcn_mfma_f32_16x16x32_bf16(ah, bh, acc[tN], 0, 0, 0);
        acc[tN] = __builtin_amdgcn_mfma_f32_16x16x32_bf16(ah, bl, acc[tN], 0, 0, 0);
        acc[tN] = __builtin_amdgcn_mfma_f32_16x16x32_bf16(al, bh, acc[tN], 0, 0, 0);
      }
    }
    __syncthreads();
  }
  const int rbase = r0 + wave * 16 + quad * 4;  // b*1024 + m
  const int bI = rbase >> 10;
#pragma unroll
  for (int tN = 0; tN < 4; tN++) {
    int u = n0 + tN * 16 + l16;
    float bu = bias[u];
#pragma unroll
    for (int i = 0; i < 4; i++) {
      int mI = (rbase + i) & 1023;
      Xpre[((size_t)mI * 8 + bI) * 256 + u] = acc[tN][i] + bu;
    }
  }
}

// ---------------- K5: sequential scan, 8 WGs (1 batch each), 8 waves --------
// Wave w owns output cols [w*32, w*32+32) = 2 n-tiles. A-tile: 2 rows
// (h_hi, h_lo), read row clamped to l16&1 -> broadcast, conflict-free.
// R17: MFMA stream split into [a1 group][quad1 epilogue][a0 group]
// [quad0 epilogue][barrier] — each quad's epilogue depends only on its
// own accumulators, so quad1's tanh/splitf/ds_writes overlap the a0 MFMA
// group on separate pipes. Per-accumulator MFMA order (bwh[kb] then
// bwl[kb], kb ascending) and per-lane recombine order unchanged ->
// bit-identical to R15. Double-buffered h, lookahead-4 c-banks, running
// pointers, in-step out-stores.
__global__ __launch_bounds__(512, 2) void rnn_scan(const u16* __restrict__ Whth,
                                                   const u16* __restrict__ Whtl,
                                                   const float* __restrict__ Xpre,
                                                   float* __restrict__ out) {
  __shared__ u16 h2[2][2 * HP_B];
  const int b = blockIdx.x;
  const int t = threadIdx.x;
  const int w = t >> 6, lane = t & 63, quad = lane >> 4, l16 = lane & 15;
  const int colbase = w * 32;
  const int col_e = colbase + quad * 16 + l16;  // valid for quads 0,1

  // Preload Wh hi+lo fragments: 2 n-tiles x 8 k-blocks, hi+lo
  bf16x8 bwh[2][8], bwl[2][8];
#pragma unroll
  for (int tN = 0; tN < 2; tN++) {
    const u16* wph = Whth + (size_t)(colbase + tN * 16 + l16) * 256 + quad * 8;
    const u16* wpl = Whtl + (size_t)(colbase + tN * 16 + l16) * 256 + quad * 8;
#pragma unroll
    for (int kb = 0; kb < 8; kb++) {
      bwh[tN][kb] = __builtin_bit_cast(bf16x8, *(const u16x8*)(wph + kb * 32));
      bwl[tN][kb] = __builtin_bit_cast(bf16x8, *(const u16x8*)(wpl + kb * 32));
    }
  }
  for (int i = t; i < 2 * 2 * HP_B; i += 512) ((u16*)h2)[i] = 0;

  // c banks 0..3: additive input for steps m4+0..m4+3 (quads 0,1 only).
  float cb[4];
  if (quad < 2) {
#pragma unroll
    for (int k = 0; k < 4; k++) cb[k] = Xpre[(size_t)k * 2048 + b * 256 + col_e];
  }
  // Running pointers (advance by constants; no per-step re-derivation).
  const float* ldp = Xpre + 4 * 2048 + b * 256 + col_e;
  float* outp = out + (size_t)b * 262144 + col_e;
  // Hoisted LDS bases. Read base: row clamped to l16&1 (broadcast dup rows).
  const u16* rb0 = &h2[0][(l16 & 1) * HP_B + quad * 8];
  const u16* rb1 = &h2[1][(l16 & 1) * HP_B + quad * 8];
  u16* wb0 = &h2[0][0];
  u16* wb1 = &h2[1][0];
  __syncthreads();

  for (int m4 = 0; m4 < 1024; m4 += 4) {
#pragma unroll
    for (int k = 0; k < 4; k++) {
      const int p = k & 1;                       // compile-time in unrolled body
      const u16* rb = p ? rb1 : rb0;
      u16* hw = p ? wb0 : wb1;                   // write the other buffer

      // Hoist all 8 A-fragment reads (one lgkmcnt ramp, MFMAs pipeline).
      bf16x8 af[8];
#pragma unroll
      for (int kb = 0; kb < 8; kb++)
        af[kb] = __builtin_bit_cast(bf16x8, *(const u16x8*)(rb + kb * 32));

      // ---- a1 group (n-tile 1), per-acc order: bwh[kb] then bwl[kb] ----
      f32x4 a1a = {0.f,0.f,0.f,0.f}, a1b = {0.f,0.f,0.f,0.f};
#pragma unroll
      for (int kb = 0; kb < 4; kb++) {
        a1a = __builtin_amdgcn_mfma_f32_16x16x32_bf16(af[kb], bwh[1][kb], a1a, 0, 0, 0);
        a1b = __builtin_amdgcn_mfma_f32_16x16x32_bf16(af[kb + 4], bwh[1][kb + 4], a1b, 0, 0, 0);
        a1a = __builtin_amdgcn_mfma_f32_16x16x32_bf16(af[kb], bwl[1][kb], a1a, 0, 0, 0);
        a1b = __builtin_amdgcn_mfma_f32_16x16x32_bf16(af[kb + 4], bwl[1][kb + 4], a1b, 0, 0, 0);
      }

      // ---- quad1 epilogue (overlaps the a0 MFMA group below) ----
      if (quad == 1) {
        float hi_part = a1a[0] + a1b[0];
        float lo_part = a1a[1] + a1b[1];
        float x = (hi_part + lo_part) + cb[k];
        float y = tanh_fast(x);
        HiLo s = splitf(y);
        hw[col_e] = s.hi;           // row 0 = h_hi
        hw[HP_B + col_e] = s.lo;    // row 1 = h_lo
        *outp = y;                  // fire-and-forget (vmcnt never drained)
        if (m4 <= 1019 - k) {       // prefetch c for step m+4
          cb[k] = *ldp;
          ldp += 2048;
        }
      }

      // ---- a0 group (n-tile 0) ----
      f32x4 a0a = {0.f,0.f,0.f,0.f}, a0b = {0.f,0.f,0.f,0.f};
#pragma unroll
      for (int kb = 0; kb < 4; kb++) {
        a0a = __builtin_amdgcn_mfma_f32_16x16x32_bf16(af[kb], bwh[0][kb], a0a, 0, 0, 0);
        a0b = __builtin_amdgcn_mfma_f32_16x16x32_bf16(af[kb + 4], bwh[0][kb + 4], a0b, 0, 0, 0);
        a0a = __builtin_amdgcn_mfma_f32_16x16x32_bf16(af[kb], bwl[0][kb], a0a, 0, 0, 0);
        a0b = __builtin_amdgcn_mfma_f32_16x16x32_bf16(af[kb + 4], bwl[0][kb + 4], a0b, 0, 0, 0);
      }

      // ---- quad0 epilogue ----
      if (quad == 0) {
        float hi_part = a0a[0] + a0b[0];
        float lo_part = a0a[1] + a0b[1];
        float x = (hi_part + lo_part) + cb[k];
        float y = tanh_fast(x);
        HiLo s = splitf(y);
        hw[col_e] = s.hi;
        hw[HP_B + col_e] = s.lo;
        *outp = y;
        if (m4 <= 1019 - k) {
          cb[k] = *ldp;
          ldp += 2048;
        }
      }
      outp += 256;
      sync_lds_only();
    }
  }
}

extern "C" void kernel_launch(void* const* d_in, const int* in_sizes, int n_in,
                              void* d_out, int out_size, void* d_ws, size_t ws_size,
                              hipStream_t stream) {
  (void)in_sizes; (void)n_in; (void)out_size; (void)ws_size;
  const float* seq   = (const float*)d_in[0];  // (8,1024,256) f32
  const float* graph = (const float*)d_in[1];  // (8,1024,1024) f32
  const float* E     = (const float*)d_in[2];  // (256,256) f32
  const float* Wx    = (const float*)d_in[3];  // (256,256) f32
  const float* Wh    = (const float*)d_in[4];  // (256,256) f32
  const float* bias  = (const float*)d_in[5];  // (256,) f32
  float* out = (float*)d_out;                  // (8,1024,256) f32

  // workspace layout (bytes): ~26 MB total
  char* w = (char*)d_ws;
  float* rnorm  = (float*)(w + 0);          //  32 KB
  u16*   Eth    = (u16*)(w + 32768);        // 128 KB
  u16*   Etl    = (u16*)(w + 163840);
  u16*   Wxth   = (u16*)(w + 294912);
  u16*   Wxtl   = (u16*)(w + 425984);
  u16*   Whth   = (u16*)(w + 557056);
  u16*   Whtl   = (u16*)(w + 688128);
  u16*   betaTh = (u16*)(w + 819200);       // 4 MB [b][u][l]
  u16*   betaTl = (u16*)(w + 5013504);      // 4 MB
  float* agg    = (float*)(w + 9207808);    // 8 MB [b][m][u]
  float* Xpre   = (float*)(w + 17596416);   // 8 MB [m][b][u]

  prep_split_rowsum<<<2816, 256, 0, stream>>>(E, Eth, Etl, Wx, Wxth, Wxtl, Wh, Whth, Whtl, graph, rnorm);
  gemm_beta<<<dim3(4, 128), 256, 0, stream>>>(seq, Eth, Etl, rnorm, betaTh, betaTl);
  gemm_agg<<<dim3(16, 4, 8), 256, 0, stream>>>(graph, betaTh, betaTl, agg);
  gemm_xpre<<<dim3(128, 4), 256, 0, stream>>>(agg, Wxth, Wxtl, bias, Xpre);
  rnn_scan<<<dim3(8), 512, 0, stream>>>(Whth, Whtl, Xpre, out);
}

// Round 7
// 789.218 us; speedup vs baseline: 1.2988x; 1.2556x over previous
//
#include <hip/hip_runtime.h>
#include <hip/hip_bf16.h>

// GraphRNN, fp32 I/O (reference dtypes are float32).
// beta = (seq @ E) / rowsum(graph); agg = graph^T @ beta (per batch);
// Xpre = agg @ Wx + b; then 1024-step scan h = tanh(Xpre_m + h @ Wh).
// MFMA path: fp32 operands split into bf16 hi+lo (rel err ~2^-18).
//
// R18: scan = R15 verbatim (620us proven; R17's quad-split epilogue cut
// the independent MFMA chains 4->2 and exposed MFMA latency, 841us ->
// REVERTED; R16's pre-MFMA global ops also reverted). Front consolidated
// 4 launches -> 2 via dependency restructuring (gaps ~20-25us each
// dominated the 158us front):
//  - rnorm folded into gemm_agg A-staging (sum_l braw*rn[l]*g[l][m] ==
//    sum_l braw*(g[l][m]*rn[l])) -> beta no longer needs rnorm;
//  - beta stages E directly with inline transpose+split (same splitf on
//    same values -> identical tile bits) -> beta no longer needs prep.
//  => front1 = {Wx/Wh splits, rowsums, raw-beta} in ONE launch (3072
//  independent blocks, no cross-block deps), then agg, xpre, scan.

typedef unsigned short u16;
typedef unsigned int u32;
typedef __bf16 bf16_t;
typedef __bf16 bf16x8 __attribute__((ext_vector_type(8)));
typedef float f32x4 __attribute__((ext_vector_type(4)));
typedef unsigned short u16x8 __attribute__((ext_vector_type(8)));
typedef unsigned short u16x4 __attribute__((ext_vector_type(4)));

#define LDS_P 72   // LDS pitch (u16) for 64-wide tiles (GEMM kernels)
#define HP_B  288  // h LDS row pitch (u16): row1 starts at dword 144 ->
                   // banks 16.. for row1 vs 0..15 for row0 chunks

struct HiLo { u16 hi, lo; };

__device__ __forceinline__ u16 f2bf(float f) {
  bf16_t h = (bf16_t)f;  // RNE
  return __builtin_bit_cast(u16, h);
}
__device__ __forceinline__ HiLo splitf(float v) {
  bf16_t h = (bf16_t)v;
  HiLo r;
  r.hi = __builtin_bit_cast(u16, h);
  r.lo = f2bf(v - (float)h);
  return r;
}
__device__ __forceinline__ float tanh_fast(float x) {
  float ax = fabsf(x);
  float e  = __expf(-2.0f * ax);
  float t  = __fdividef(1.0f - e, 1.0f + e);
  return copysignf(t, x);
}
// Barrier with LDS-only visibility (drains lgkmcnt, not vmcnt).
__device__ __forceinline__ void sync_lds_only() {
  __asm__ volatile("s_waitcnt lgkmcnt(0)\ns_barrier" ::: "memory");
}

// ---------------- K1 front1: Wx/Wh splits + rowsums + raw-beta --------------
// bid <  512 : transpose+split Wx (bid<256) / Wh (bid>=256), col u=bid&255.
// 512..2559  : rnorm[row] = 1/max(rowsum, 1e-7), 4 rows/block.
// 2560..3071 : raw betaT[b][u][l] = hi/lo of (seq@E)[b,l,u] (NO rnorm);
//              E staged directly from global with inline transpose+split.
__global__ __launch_bounds__(256, 2) void front1(
    const float* __restrict__ Wx, u16* __restrict__ Wxth, u16* __restrict__ Wxtl,
    const float* __restrict__ Wh, u16* __restrict__ Whth, u16* __restrict__ Whtl,
    const float* __restrict__ graph, float* __restrict__ rnorm,
    const float* __restrict__ seq, const float* __restrict__ E,
    u16* __restrict__ betaTh, u16* __restrict__ betaTl) {
  __shared__ u16 Ah[64 * LDS_P], Al[64 * LDS_P];
  __shared__ u16 Bh[64 * LDS_P], Bl[64 * LDS_P];
  const int bid = blockIdx.x;
  const int t = threadIdx.x;

  if (bid < 512) {  // weight transpose+split
    const int u = bid & 255, d = t;
    const float* s; u16 *dh, *dl;
    if (bid < 256) { s = Wx; dh = Wxth; dl = Wxtl; }
    else           { s = Wh; dh = Whth; dl = Whtl; }
    HiLo r = splitf(s[d * 256 + u]);
    dh[u * 256 + d] = r.hi;
    dl[u * 256 + d] = r.lo;
    return;
  }
  if (bid < 2560) {  // graph row-sums
    const int wave = t >> 6, lane = t & 63;
    const int row = (bid - 512) * 4 + wave;  // 0..8191
    const float* p = graph + (size_t)row * 1024 + lane * 16;
    float s = 0.f;
#pragma unroll
    for (int c = 0; c < 4; c++) {
      f32x4 v = *(const f32x4*)(p + c * 4);
#pragma unroll
      for (int j = 0; j < 4; j++) s += v[j];
    }
#pragma unroll
    for (int off = 32; off > 0; off >>= 1) s += __shfl_xor(s, off);
    if (lane == 0) rnorm[row] = 1.0f / fmaxf(s, 1e-7f);
    return;
  }

  // ---- raw beta: (seq @ E), 64x64 tile per block ----
  const int v = bid - 2560;                  // 0..511
  const int wave = t >> 6, lane = t & 63, quad = lane >> 4, l16 = lane & 15;
  const int n0 = (v & 3) * 64, r0 = (v >> 2) * 64;  // same-r0 blocks adjacent
  f32x4 acc[4];
#pragma unroll
  for (int i = 0; i < 4; i++) acc[i] = (f32x4){0.f, 0.f, 0.f, 0.f};

  for (int kb = 0; kb < 256; kb += 64) {
#pragma unroll
    for (int cc = 0; cc < 4; cc++) {  // A: seq rows, split to hi/lo
      int c = t + cc * 256;
      int r = c >> 4, c4 = c & 15;
      f32x4 vv = *(const f32x4*)(seq + (size_t)(r0 + r) * 256 + kb + c4 * 4);
      u16x4 hi, lo;
#pragma unroll
      for (int j = 0; j < 4; j++) {
        HiLo s = splitf(vv[j]);
        hi[j] = s.hi; lo[j] = s.lo;
      }
      *(u16x4*)(Ah + r * LDS_P + c4 * 4) = hi;
      *(u16x4*)(Al + r * LDS_P + c4 * 4) = lo;
    }
#pragma unroll
    for (int cc = 0; cc < 4; cc++) {  // B: E read [d][u], stored [u][d]
      int c = t + cc * 256;
      int r = c >> 4, c4 = c & 15;    // r = d_local, c4 = u-chunk of 4
      f32x4 vv = *(const f32x4*)(E + (size_t)(kb + r) * 256 + n0 + c4 * 4);
#pragma unroll
      for (int j = 0; j < 4; j++) {
        HiLo s = splitf(vv[j]);
        Bh[(c4 * 4 + j) * LDS_P + r] = s.hi;
        Bl[(c4 * 4 + j) * LDS_P + r] = s.lo;
      }
    }
    __syncthreads();
#pragma unroll
    for (int kk = 0; kk < 64; kk += 32) {
      bf16x8 ah = __builtin_bit_cast(bf16x8, *(const u16x8*)(Ah + (wave * 16 + l16) * LDS_P + kk + quad * 8));
      bf16x8 al = __builtin_bit_cast(bf16x8, *(const u16x8*)(Al + (wave * 16 + l16) * LDS_P + kk + quad * 8));
#pragma unroll
      for (int tN = 0; tN < 4; tN++) {
        bf16x8 bh = __builtin_bit_cast(bf16x8, *(const u16x8*)(Bh + (tN * 16 + l16) * LDS_P + kk + quad * 8));
        bf16x8 bl = __builtin_bit_cast(bf16x8, *(const u16x8*)(Bl + (tN * 16 + l16) * LDS_P + kk + quad * 8));
        acc[tN] = __builtin_amdgcn_mfma_f32_16x16x32_bf16(ah, bh, acc[tN], 0, 0, 0);
        acc[tN] = __builtin_amdgcn_mfma_f32_16x16x32_bf16(ah, bl, acc[tN], 0, 0, 0);
        acc[tN] = __builtin_amdgcn_mfma_f32_16x16x32_bf16(al, bh, acc[tN], 0, 0, 0);
      }
    }
    __syncthreads();
  }
  const int rbase = r0 + wave * 16 + quad * 4;  // b*1024 + l, 4 consecutive l
  const int bI = rbase >> 10, lI = rbase & 1023;
#pragma unroll
  for (int tN = 0; tN < 4; tN++) {
    int u = n0 + tN * 16 + l16;
    u16x4 hv, lv;
#pragma unroll
    for (int i = 0; i < 4; i++) {
      HiLo s = splitf(acc[tN][i]);   // raw beta (rnorm folded into agg)
      hv[i] = s.hi; lv[i] = s.lo;
    }
    size_t off = ((size_t)bI << 18) + (size_t)u * 1024 + lI;
    *(u16x4*)(betaTh + off) = hv;
    *(u16x4*)(betaTl + off) = lv;
  }
}

// ---------------- K2: agg[b][m][u] = sum_l (g[l][m]*rn[l]) * braw[l][u] -----
__global__ __launch_bounds__(256, 2) void gemm_agg(const float* __restrict__ graph,
                                                   const u16* __restrict__ betaTh,
                                                   const u16* __restrict__ betaTl,
                                                   const float* __restrict__ rnorm,
                                                   float* __restrict__ agg) {
  __shared__ u16 Ah[64 * LDS_P], Al[64 * LDS_P];
  __shared__ u16 Bh[64 * LDS_P], Bl[64 * LDS_P];
  const int t = threadIdx.x;
  const int wave = t >> 6, lane = t & 63, quad = lane >> 4, l16 = lane & 15;
  const int m0 = blockIdx.x * 64, n0 = blockIdx.y * 64, b = blockIdx.z;
  const float* g = graph + (size_t)b * (1024 * 1024);
  const float* rnb = rnorm + b * 1024;
  const size_t bt = (size_t)b << 18;
  f32x4 acc[4];
#pragma unroll
  for (int i = 0; i < 4; i++) acc[i] = (f32x4){0.f, 0.f, 0.f, 0.f};

  for (int kb = 0; kb < 1024; kb += 64) {
#pragma unroll
    for (int cc = 0; cc < 4; cc++) {
      int c = t + cc * 256;
      int r = c >> 4, c4 = c & 15;  // r = l_local, c4 = m-chunk of 4
      f32x4 v = *(const f32x4*)(g + (size_t)(kb + r) * 1024 + m0 + c4 * 4);
      float rn = rnb[kb + r];       // broadcast (16 lanes share r)
#pragma unroll
      for (int j = 0; j < 4; j++) {
        HiLo s = splitf(v[j] * rn);
        Ah[(c4 * 4 + j) * LDS_P + r] = s.hi;  // A[m][l] = graph[l][m]*rn[l]
        Al[(c4 * 4 + j) * LDS_P + r] = s.lo;
      }
    }
#pragma unroll
    for (int cc = 0; cc < 2; cc++) {
      int c = t + cc * 256;
      int r = c >> 3, c8 = c & 7;
      *(u16x8*)(Bh + r * LDS_P + c8 * 8) =
          *(const u16x8*)(betaTh + bt + (size_t)(n0 + r) * 1024 + kb + c8 * 8);
      *(u16x8*)(Bl + r * LDS_P + c8 * 8) =
          *(const u16x8*)(betaTl + bt + (size_t)(n0 + r) * 1024 + kb + c8 * 8);
    }
    __syncthreads();
#pragma unroll
    for (int kk = 0; kk < 64; kk += 32) {
      bf16x8 ah = __builtin_bit_cast(bf16x8, *(const u16x8*)(Ah + (wave * 16 + l16) * LDS_P + kk + quad * 8));
      bf16x8 al = __builtin_bit_cast(bf16x8, *(const u16x8*)(Al + (wave * 16 + l16) * LDS_P + kk + quad * 8));
#pragma unroll
      for (int tN = 0; tN < 4; tN++) {
        bf16x8 bh = __builtin_bit_cast(bf16x8, *(const u16x8*)(Bh + (tN * 16 + l16) * LDS_P + kk + quad * 8));
        bf16x8 bl = __builtin_bit_cast(bf16x8, *(const u16x8*)(Bl + (tN * 16 + l16) * LDS_P + kk + quad * 8));
        acc[tN] = __builtin_amdgcn_mfma_f32_16x16x32_bf16(ah, bh, acc[tN], 0, 0, 0);
        acc[tN] = __builtin_amdgcn_mfma_f32_16x16x32_bf16(ah, bl, acc[tN], 0, 0, 0);
        acc[tN] = __builtin_amdgcn_mfma_f32_16x16x32_bf16(al, bh, acc[tN], 0, 0, 0);
      }
    }
    __syncthreads();
  }
  const int mbase = m0 + wave * 16 + quad * 4;
#pragma unroll
  for (int tN = 0; tN < 4; tN++) {
    int u = n0 + tN * 16 + l16;
#pragma unroll
    for (int i = 0; i < 4; i++)
      agg[((size_t)b * 1024 + mbase + i) * 256 + u] = acc[tN][i];
  }
}

// ---------------- K3: Xpre[m][b][u] = (agg @ Wx)[b,m,u] + bias[u] (fp32) ----
__global__ __launch_bounds__(256, 2) void gemm_xpre(const float* __restrict__ agg,
                                                    const u16* __restrict__ Wxth,
                                                    const u16* __restrict__ Wxtl,
                                                    const float* __restrict__ bias,
                                                    float* __restrict__ Xpre) {
  __shared__ u16 Ah[64 * LDS_P], Al[64 * LDS_P];
  __shared__ u16 Bh[64 * LDS_P], Bl[64 * LDS_P];
  const int t = threadIdx.x;
  const int wave = t >> 6, lane = t & 63, quad = lane >> 4, l16 = lane & 15;
  const int r0 = blockIdx.x * 64, n0 = blockIdx.y * 64;
  f32x4 acc[4];
#pragma unroll
  for (int i = 0; i < 4; i++) acc[i] = (f32x4){0.f, 0.f, 0.f, 0.f};

  for (int kb = 0; kb < 256; kb += 64) {
#pragma unroll
    for (int cc = 0; cc < 4; cc++) {
      int c = t + cc * 256;
      int r = c >> 4, c4 = c & 15;
      f32x4 v = *(const f32x4*)(agg + (size_t)(r0 + r) * 256 + kb + c4 * 4);
      u16x4 hi, lo;
#pragma unroll
      for (int j = 0; j < 4; j++) {
        HiLo s = splitf(v[j]);
        hi[j] = s.hi; lo[j] = s.lo;
      }
      *(u16x4*)(Ah + r * LDS_P + c4 * 4) = hi;
      *(u16x4*)(Al + r * LDS_P + c4 * 4) = lo;
    }
#pragma unroll
    for (int cc = 0; cc < 2; cc++) {
      int c = t + cc * 256;
      int r = c >> 3, c8 = c & 7;
      *(u16x8*)(Bh + r * LDS_P + c8 * 8) =
          *(const u16x8*)(Wxth + (size_t)(n0 + r) * 256 + kb + c8 * 8);
      *(u16x8*)(Bl + r * LDS_P + c8 * 8) =
          *(const u16x8*)(Wxtl + (size_t)(n0 + r) * 256 + kb + c8 * 8);
    }
    __syncthreads();
#pragma unroll
    for (int kk = 0; kk < 64; kk += 32) {
      bf16x8 ah = __builtin_bit_cast(bf16x8, *(const u16x8*)(Ah + (wave * 16 + l16) * LDS_P + kk + quad * 8));
      bf16x8 al = __builtin_bit_cast(bf16x8, *(const u16x8*)(Al + (wave * 16 + l16) * LDS_P + kk + quad * 8));
#pragma unroll
      for (int tN = 0; tN < 4; tN++) {
        bf16x8 bh = __builtin_bit_cast(bf16x8, *(const u16x8*)(Bh + (tN * 16 + l16) * LDS_P + kk + quad * 8));
        bf16x8 bl = __builtin_bit_cast(bf16x8, *(const u16x8*)(Bl + (tN * 16 + l16) * LDS_P + kk + quad * 8));
        acc[tN] = __builtin_amdgcn_mfma_f32_16x16x32_bf16(ah, bh, acc[tN], 0, 0, 0);
        acc[tN] = __builtin_amdgcn_mfma_f32_16x16x32_bf16(ah, bl, acc[tN], 0, 0, 0);
        acc[tN] = __builtin_amdgcn_mfma_f32_16x16x32_bf16(al, bh, acc[tN], 0, 0, 0);
      }
    }
    __syncthreads();
  }
  const int rbase = r0 + wave * 16 + quad * 4;  // b*1024 + m
  const int bI = rbase >> 10;
#pragma unroll
  for (int tN = 0; tN < 4; tN++) {
    int u = n0 + tN * 16 + l16;
    float bu = bias[u];
#pragma unroll
    for (int i = 0; i < 4; i++) {
      int mI = (rbase + i) & 1023;
      Xpre[((size_t)mI * 8 + bI) * 256 + u] = acc[tN][i] + bu;
    }
  }
}

// ---------------- K4: sequential scan — R15 VERBATIM (620us proven) ---------
// 8 WGs (1 batch each), 8 waves. Wave w owns cols [w*32,w*32+32) = 2
// n-tiles. A-tile: 2 rows (h hi/lo), read row clamped to l16&1 ->
// broadcast, conflict-free. Quads 0/1 both hold valid (hi,lo) in C regs
// [0],[1]; quad0 -> tile0, quad1 -> tile1 -> 1 tanh chain/lane. MFMA
// interleave keeps 4 independent accumulator chains (a0a,a1a,a0b,a1b) —
// REQUIRED (R17: 2 chains exposed MFMA latency, +35%). All 8 ds_reads
// hoisted to step top. Nothing precedes MFMA issue (R16 lesson).
__global__ __launch_bounds__(512, 2) void rnn_scan(const u16* __restrict__ Whth,
                                                   const u16* __restrict__ Whtl,
                                                   const float* __restrict__ Xpre,
                                                   float* __restrict__ out) {
  __shared__ u16 h2[2][2 * HP_B];
  const int b = blockIdx.x;
  const int t = threadIdx.x;
  const int w = t >> 6, lane = t & 63, quad = lane >> 4, l16 = lane & 15;
  const int colbase = w * 32;
  const bool epi = (quad < 2);           // quad0 -> tile0, quad1 -> tile1
  const int col_e = colbase + quad * 16 + l16;  // valid for epi lanes

  // Preload Wh hi+lo fragments: 2 n-tiles x 8 k-blocks, hi+lo
  bf16x8 bwh[2][8], bwl[2][8];
#pragma unroll
  for (int tN = 0; tN < 2; tN++) {
    const u16* wph = Whth + (size_t)(colbase + tN * 16 + l16) * 256 + quad * 8;
    const u16* wpl = Whtl + (size_t)(colbase + tN * 16 + l16) * 256 + quad * 8;
#pragma unroll
    for (int kb = 0; kb < 8; kb++) {
      bwh[tN][kb] = __builtin_bit_cast(bf16x8, *(const u16x8*)(wph + kb * 32));
      bwl[tN][kb] = __builtin_bit_cast(bf16x8, *(const u16x8*)(wpl + kb * 32));
    }
  }
  for (int i = t; i < 2 * 2 * HP_B; i += 512) ((u16*)h2)[i] = 0;

  // c banks 0..3: additive input for steps m4+0..m4+3 (epi lanes only).
  float cb[4];
  if (epi) {
#pragma unroll
    for (int k = 0; k < 4; k++) cb[k] = Xpre[(size_t)k * 2048 + b * 256 + col_e];
  }
  // Running pointers (advance by constants; no per-step re-derivation).
  const float* ldp = Xpre + 4 * 2048 + b * 256 + col_e;
  float* outp = out + (size_t)b * 262144 + col_e;
  // Hoisted LDS bases. Read base: row clamped to l16&1 (broadcast dup rows).
  const u16* rb0 = &h2[0][(l16 & 1) * HP_B + quad * 8];
  const u16* rb1 = &h2[1][(l16 & 1) * HP_B + quad * 8];
  u16* wb0 = &h2[0][0];
  u16* wb1 = &h2[1][0];
  __syncthreads();

  for (int m4 = 0; m4 < 1024; m4 += 4) {
#pragma unroll
    for (int k = 0; k < 4; k++) {
      const int p = k & 1;                       // compile-time in unrolled body
      const u16* rb = p ? rb1 : rb0;
      u16* hw = p ? wb0 : wb1;                   // write the other buffer

      // Hoist all 8 A-fragment reads (one lgkmcnt ramp, MFMAs pipeline).
      bf16x8 af[8];
#pragma unroll
      for (int kb = 0; kb < 8; kb++)
        af[kb] = __builtin_bit_cast(bf16x8, *(const u16x8*)(rb + kb * 32));

      f32x4 a0a = {0.f,0.f,0.f,0.f}, a0b = {0.f,0.f,0.f,0.f};
      f32x4 a1a = {0.f,0.f,0.f,0.f}, a1b = {0.f,0.f,0.f,0.f};
#pragma unroll
      for (int kb = 0; kb < 4; kb++) {
        a0a = __builtin_amdgcn_mfma_f32_16x16x32_bf16(af[kb], bwh[0][kb], a0a, 0, 0, 0);
        a1a = __builtin_amdgcn_mfma_f32_16x16x32_bf16(af[kb], bwh[1][kb], a1a, 0, 0, 0);
        a0b = __builtin_amdgcn_mfma_f32_16x16x32_bf16(af[kb + 4], bwh[0][kb + 4], a0b, 0, 0, 0);
        a1b = __builtin_amdgcn_mfma_f32_16x16x32_bf16(af[kb + 4], bwh[1][kb + 4], a1b, 0, 0, 0);
        a0a = __builtin_amdgcn_mfma_f32_16x16x32_bf16(af[kb], bwl[0][kb], a0a, 0, 0, 0);
        a1a = __builtin_amdgcn_mfma_f32_16x16x32_bf16(af[kb], bwl[1][kb], a1a, 0, 0, 0);
        a0b = __builtin_amdgcn_mfma_f32_16x16x32_bf16(af[kb + 4], bwl[0][kb + 4], a0b, 0, 0, 0);
        a1b = __builtin_amdgcn_mfma_f32_16x16x32_bf16(af[kb + 4], bwl[1][kb + 4], a1b, 0, 0, 0);
      }

      // Epilogue distributed: quad0 uses (a0a,a0b), quad1 uses (a1a,a1b).
      if (epi) {
        float sA0 = quad ? a1a[0] : a0a[0];
        float sA1 = quad ? a1a[1] : a0a[1];
        float sB0 = quad ? a1b[0] : a0b[0];
        float sB1 = quad ? a1b[1] : a0b[1];
        float hi_part = sA0 + sB0;
        float lo_part = sA1 + sB1;
        float x = (hi_part + lo_part) + cb[k];
        float y = tanh_fast(x);
        HiLo s = splitf(y);
        hw[col_e] = s.hi;           // row 0 = h_hi
        hw[HP_B + col_e] = s.lo;    // row 1 = h_lo
        *outp = y;                  // fire-and-forget (vmcnt never drained)
        // Prefetch c for step m+4 into the bank just consumed.
        if (m4 <= 1019 - k) {
          cb[k] = *ldp;
          ldp += 2048;
        }
      }
      outp += 256;
      sync_lds_only();
    }
  }
}

extern "C" void kernel_launch(void* const* d_in, const int* in_sizes, int n_in,
                              void* d_out, int out_size, void* d_ws, size_t ws_size,
                              hipStream_t stream) {
  (void)in_sizes; (void)n_in; (void)out_size; (void)ws_size;
  const float* seq   = (const float*)d_in[0];  // (8,1024,256) f32
  const float* graph = (const float*)d_in[1];  // (8,1024,1024) f32
  const float* E     = (const float*)d_in[2];  // (256,256) f32
  const float* Wx    = (const float*)d_in[3];  // (256,256) f32
  const float* Wh    = (const float*)d_in[4];  // (256,256) f32
  const float* bias  = (const float*)d_in[5];  // (256,) f32
  float* out = (float*)d_out;                  // (8,1024,256) f32

  // workspace layout (bytes): ~26 MB total
  char* w = (char*)d_ws;
  float* rnorm  = (float*)(w + 0);          //  32 KB
  u16*   Wxth   = (u16*)(w + 294912);       // 128 KB each
  u16*   Wxtl   = (u16*)(w + 425984);
  u16*   Whth   = (u16*)(w + 557056);
  u16*   Whtl   = (u16*)(w + 688128);
  u16*   betaTh = (u16*)(w + 819200);       // 4 MB [b][u][l] (raw, no rnorm)
  u16*   betaTl = (u16*)(w + 5013504);      // 4 MB
  float* agg    = (float*)(w + 9207808);    // 8 MB [b][m][u]
  float* Xpre   = (float*)(w + 17596416);   // 8 MB [m][b][u]

  front1<<<3072, 256, 0, stream>>>(Wx, Wxth, Wxtl, Wh, Whth, Whtl,
                                   graph, rnorm, seq, E, betaTh, betaTl);
  gemm_agg<<<dim3(16, 4, 8), 256, 0, stream>>>(graph, betaTh, betaTl, rnorm, agg);
  gemm_xpre<<<dim3(128, 4), 256, 0, stream>>>(agg, Wxth, Wxtl, bias, Xpre);
  rnn_scan<<<dim3(8), 512, 0, stream>>>(Whth, Whtl, Xpre, out);
}

// Round 8
// 773.505 us; speedup vs baseline: 1.3252x; 1.0203x over previous
//
#include <hip/hip_runtime.h>
#include <hip/hip_bf16.h>

// GraphRNN, fp32 I/O (reference dtypes are float32).
// beta = (seq @ E) / rowsum(graph); agg = graph^T @ beta (per batch);
// Xpre = agg @ Wx + b; then 1024-step scan h = tanh(Xpre_m + h @ Wh).
// MFMA path: fp32 operands split into bf16 hi+lo (rel err ~2^-18).
//
// R19: scan = R15/R18 verbatim (622us; R16/R17 scan edits both regressed
// -> frozen). Front GEMMs restructured to kill A-restaging redundancy
// (R18 showed gaps are small; the ~150us front is kernel duration, and
// each old 64x64-block grid re-staged the same A-tile 4x across n-blocks:
// agg read+splitf'd the 33.5MB graph 4x = 134MB HBM + 4x staging VALU).
// New shape: 64x128 output stripe per block, 512 thr / 8 waves, wave w =
// (m-sub w&3, n-half w>>2), acc[4]/wave, A staged once per 2 n-groups,
// B staged 128 rows. Same splitf on same values, same 3-MFMA pattern ->
// bit-identical. Grids: beta 256 (in front1, dispatched first), agg
// (16,2,8), xpre (128,2) — 1 block/CU, 2 waves/SIMD.

typedef unsigned short u16;
typedef unsigned int u32;
typedef __bf16 bf16_t;
typedef __bf16 bf16x8 __attribute__((ext_vector_type(8)));
typedef float f32x4 __attribute__((ext_vector_type(4)));
typedef unsigned short u16x8 __attribute__((ext_vector_type(8)));
typedef unsigned short u16x4 __attribute__((ext_vector_type(4)));

#define LDS_P 72   // LDS pitch (u16) for staged tiles
#define HP_B  288  // h LDS row pitch (u16) in the scan

struct HiLo { u16 hi, lo; };

__device__ __forceinline__ u16 f2bf(float f) {
  bf16_t h = (bf16_t)f;  // RNE
  return __builtin_bit_cast(u16, h);
}
__device__ __forceinline__ HiLo splitf(float v) {
  bf16_t h = (bf16_t)v;
  HiLo r;
  r.hi = __builtin_bit_cast(u16, h);
  r.lo = f2bf(v - (float)h);
  return r;
}
__device__ __forceinline__ float tanh_fast(float x) {
  float ax = fabsf(x);
  float e  = __expf(-2.0f * ax);
  float t  = __fdividef(1.0f - e, 1.0f + e);
  return copysignf(t, x);
}
// Barrier with LDS-only visibility (drains lgkmcnt, not vmcnt).
__device__ __forceinline__ void sync_lds_only() {
  __asm__ volatile("s_waitcnt lgkmcnt(0)\ns_barrier" ::: "memory");
}

// ---------------- K1 front1 (512 thr): beta + weight splits + rowsums -------
// bid <  256 : raw betaT 64x128 stripe (dispatched FIRST — long poles).
// 256..511   : transpose+split Wx/Wh, 2 columns per block.
// 512..1535  : rnorm rows (bid-512)*8 .. +8 (one row per wave).
__global__ __launch_bounds__(512, 2) void front1(
    const float* __restrict__ Wx, u16* __restrict__ Wxth, u16* __restrict__ Wxtl,
    const float* __restrict__ Wh, u16* __restrict__ Whth, u16* __restrict__ Whtl,
    const float* __restrict__ graph, float* __restrict__ rnorm,
    const float* __restrict__ seq, const float* __restrict__ E,
    u16* __restrict__ betaTh, u16* __restrict__ betaTl) {
  __shared__ u16 Ah[64 * LDS_P], Al[64 * LDS_P];
  __shared__ u16 Bh[128 * LDS_P], Bl[128 * LDS_P];
  const int bid = blockIdx.x;
  const int t = threadIdx.x;

  if (bid >= 256 && bid < 512) {  // weight transpose+split, 2 cols/block
    const int wbid = bid - 256;
    const int u = ((wbid & 127) << 1) + (t >> 8), d = t & 255;
    const float* s; u16 *dh, *dl;
    if (wbid < 128) { s = Wx; dh = Wxth; dl = Wxtl; }
    else            { s = Wh; dh = Whth; dl = Whtl; }
    HiLo r = splitf(s[d * 256 + u]);
    dh[u * 256 + d] = r.hi;
    dl[u * 256 + d] = r.lo;
    return;
  }
  if (bid >= 512) {  // graph row-sums, 8 rows/block
    const int wave = t >> 6, lane = t & 63;
    const int row = (bid - 512) * 8 + wave;  // 0..8191
    const float* p = graph + (size_t)row * 1024 + lane * 16;
    float s = 0.f;
#pragma unroll
    for (int c = 0; c < 4; c++) {
      f32x4 v = *(const f32x4*)(p + c * 4);
#pragma unroll
      for (int j = 0; j < 4; j++) s += v[j];
    }
#pragma unroll
    for (int off = 32; off > 0; off >>= 1) s += __shfl_xor(s, off);
    if (lane == 0) rnorm[row] = 1.0f / fmaxf(s, 1e-7f);
    return;
  }

  // ---- raw beta (seq @ E): 64 rows x 128 u per block ----
  const int v = bid;                          // 0..255
  const int w = t >> 6, lane = t & 63, quad = lane >> 4, l16 = lane & 15;
  const int msub = w & 3, nsub = w >> 2;
  const int r0 = (v >> 1) * 64, n_base = (v & 1) * 128;
  f32x4 acc[4];
#pragma unroll
  for (int i = 0; i < 4; i++) acc[i] = (f32x4){0.f, 0.f, 0.f, 0.f};

  for (int kb = 0; kb < 256; kb += 64) {
#pragma unroll
    for (int cc = 0; cc < 2; cc++) {  // A: seq 64 rows x 64 k, split hi/lo
      int c = t + cc * 512;
      int r = c >> 4, c4 = c & 15;
      f32x4 vv = *(const f32x4*)(seq + (size_t)(r0 + r) * 256 + kb + c4 * 4);
      u16x4 hi, lo;
#pragma unroll
      for (int j = 0; j < 4; j++) {
        HiLo s = splitf(vv[j]);
        hi[j] = s.hi; lo[j] = s.lo;
      }
      *(u16x4*)(Ah + r * LDS_P + c4 * 4) = hi;
      *(u16x4*)(Al + r * LDS_P + c4 * 4) = lo;
    }
#pragma unroll
    for (int cc = 0; cc < 4; cc++) {  // B: E[d][u] 64 d x 128 u, transposed
      int c = t + cc * 512;
      int r = c >> 5, c5 = c & 31;    // r = d_local, c5 = u-chunk of 4
      f32x4 vv = *(const f32x4*)(E + (size_t)(kb + r) * 256 + n_base + c5 * 4);
#pragma unroll
      for (int j = 0; j < 4; j++) {
        HiLo s = splitf(vv[j]);
        Bh[(c5 * 4 + j) * LDS_P + r] = s.hi;
        Bl[(c5 * 4 + j) * LDS_P + r] = s.lo;
      }
    }
    __syncthreads();
#pragma unroll
    for (int kk = 0; kk < 64; kk += 32) {
      bf16x8 ah = __builtin_bit_cast(bf16x8, *(const u16x8*)(Ah + (msub * 16 + l16) * LDS_P + kk + quad * 8));
      bf16x8 al = __builtin_bit_cast(bf16x8, *(const u16x8*)(Al + (msub * 16 + l16) * LDS_P + kk + quad * 8));
#pragma unroll
      for (int tN = 0; tN < 4; tN++) {
        int brow = nsub * 64 + tN * 16 + l16;
        bf16x8 bh = __builtin_bit_cast(bf16x8, *(const u16x8*)(Bh + brow * LDS_P + kk + quad * 8));
        bf16x8 bl = __builtin_bit_cast(bf16x8, *(const u16x8*)(Bl + brow * LDS_P + kk + quad * 8));
        acc[tN] = __builtin_amdgcn_mfma_f32_16x16x32_bf16(ah, bh, acc[tN], 0, 0, 0);
        acc[tN] = __builtin_amdgcn_mfma_f32_16x16x32_bf16(ah, bl, acc[tN], 0, 0, 0);
        acc[tN] = __builtin_amdgcn_mfma_f32_16x16x32_bf16(al, bh, acc[tN], 0, 0, 0);
      }
    }
    __syncthreads();
  }
  const int rbase = r0 + msub * 16 + quad * 4;  // b*1024 + l
  const int bI = rbase >> 10, lI = rbase & 1023;
#pragma unroll
  for (int tN = 0; tN < 4; tN++) {
    int u = n_base + nsub * 64 + tN * 16 + l16;
    u16x4 hv, lv;
#pragma unroll
    for (int i = 0; i < 4; i++) {
      HiLo s = splitf(acc[tN][i]);   // raw beta (rnorm folded into agg)
      hv[i] = s.hi; lv[i] = s.lo;
    }
    size_t off = ((size_t)bI << 18) + (size_t)u * 1024 + lI;
    *(u16x4*)(betaTh + off) = hv;
    *(u16x4*)(betaTl + off) = lv;
  }
}

// ---------------- K2: agg[b][m][u] = sum_l (g[l][m]*rn[l]) * braw[l][u] -----
// 64 m x 128 u per block; A (graph^T, rn-folded) staged ONCE per stripe.
__global__ __launch_bounds__(512, 2) void gemm_agg(const float* __restrict__ graph,
                                                   const u16* __restrict__ betaTh,
                                                   const u16* __restrict__ betaTl,
                                                   const float* __restrict__ rnorm,
                                                   float* __restrict__ agg) {
  __shared__ u16 Ah[64 * LDS_P], Al[64 * LDS_P];
  __shared__ u16 Bh[128 * LDS_P], Bl[128 * LDS_P];
  const int t = threadIdx.x;
  const int w = t >> 6, lane = t & 63, quad = lane >> 4, l16 = lane & 15;
  const int msub = w & 3, nsub = w >> 2;
  const int m0 = blockIdx.x * 64, n_base = blockIdx.y * 128, b = blockIdx.z;
  const float* g = graph + (size_t)b * (1024 * 1024);
  const float* rnb = rnorm + b * 1024;
  const size_t bt = (size_t)b << 18;
  f32x4 acc[4];
#pragma unroll
  for (int i = 0; i < 4; i++) acc[i] = (f32x4){0.f, 0.f, 0.f, 0.f};

  for (int kb = 0; kb < 1024; kb += 64) {
#pragma unroll
    for (int cc = 0; cc < 2; cc++) {  // A: graph 64 l x 64 m, transposed+rn
      int c = t + cc * 512;
      int r = c >> 4, c4 = c & 15;    // r = l_local, c4 = m-chunk of 4
      f32x4 vv = *(const f32x4*)(g + (size_t)(kb + r) * 1024 + m0 + c4 * 4);
      float rn = rnb[kb + r];
#pragma unroll
      for (int j = 0; j < 4; j++) {
        HiLo s = splitf(vv[j] * rn);
        Ah[(c4 * 4 + j) * LDS_P + r] = s.hi;  // A[m][l]
        Al[(c4 * 4 + j) * LDS_P + r] = s.lo;
      }
    }
#pragma unroll
    for (int cc = 0; cc < 2; cc++) {  // B: betaT 128 u-rows x 64 k copy
      int c = t + cc * 512;
      int r = c >> 3, c8 = c & 7;
      *(u16x8*)(Bh + r * LDS_P + c8 * 8) =
          *(const u16x8*)(betaTh + bt + (size_t)(n_base + r) * 1024 + kb + c8 * 8);
      *(u16x8*)(Bl + r * LDS_P + c8 * 8) =
          *(const u16x8*)(betaTl + bt + (size_t)(n_base + r) * 1024 + kb + c8 * 8);
    }
    __syncthreads();
#pragma unroll
    for (int kk = 0; kk < 64; kk += 32) {
      bf16x8 ah = __builtin_bit_cast(bf16x8, *(const u16x8*)(Ah + (msub * 16 + l16) * LDS_P + kk + quad * 8));
      bf16x8 al = __builtin_bit_cast(bf16x8, *(const u16x8*)(Al + (msub * 16 + l16) * LDS_P + kk + quad * 8));
#pragma unroll
      for (int tN = 0; tN < 4; tN++) {
        int brow = nsub * 64 + tN * 16 + l16;
        bf16x8 bh = __builtin_bit_cast(bf16x8, *(const u16x8*)(Bh + brow * LDS_P + kk + quad * 8));
        bf16x8 bl = __builtin_bit_cast(bf16x8, *(const u16x8*)(Bl + brow * LDS_P + kk + quad * 8));
        acc[tN] = __builtin_amdgcn_mfma_f32_16x16x32_bf16(ah, bh, acc[tN], 0, 0, 0);
        acc[tN] = __builtin_amdgcn_mfma_f32_16x16x32_bf16(ah, bl, acc[tN], 0, 0, 0);
        acc[tN] = __builtin_amdgcn_mfma_f32_16x16x32_bf16(al, bh, acc[tN], 0, 0, 0);
      }
    }
    __syncthreads();
  }
  const int mbase = m0 + msub * 16 + quad * 4;
#pragma unroll
  for (int tN = 0; tN < 4; tN++) {
    int u = n_base + nsub * 64 + tN * 16 + l16;
#pragma unroll
    for (int i = 0; i < 4; i++)
      agg[((size_t)b * 1024 + mbase + i) * 256 + u] = acc[tN][i];
  }
}

// ---------------- K3: Xpre[m][b][u] = (agg @ Wx)[b,m,u] + bias[u] -----------
__global__ __launch_bounds__(512, 2) void gemm_xpre(const float* __restrict__ agg,
                                                    const u16* __restrict__ Wxth,
                                                    const u16* __restrict__ Wxtl,
                                                    const float* __restrict__ bias,
                                                    float* __restrict__ Xpre) {
  __shared__ u16 Ah[64 * LDS_P], Al[64 * LDS_P];
  __shared__ u16 Bh[128 * LDS_P], Bl[128 * LDS_P];
  const int t = threadIdx.x;
  const int w = t >> 6, lane = t & 63, quad = lane >> 4, l16 = lane & 15;
  const int msub = w & 3, nsub = w >> 2;
  const int r0 = blockIdx.x * 64, n_base = blockIdx.y * 128;
  f32x4 acc[4];
#pragma unroll
  for (int i = 0; i < 4; i++) acc[i] = (f32x4){0.f, 0.f, 0.f, 0.f};

  for (int kb = 0; kb < 256; kb += 64) {
#pragma unroll
    for (int cc = 0; cc < 2; cc++) {  // A: agg 64 rows x 64 k, split hi/lo
      int c = t + cc * 512;
      int r = c >> 4, c4 = c & 15;
      f32x4 vv = *(const f32x4*)(agg + (size_t)(r0 + r) * 256 + kb + c4 * 4);
      u16x4 hi, lo;
#pragma unroll
      for (int j = 0; j < 4; j++) {
        HiLo s = splitf(vv[j]);
        hi[j] = s.hi; lo[j] = s.lo;
      }
      *(u16x4*)(Ah + r * LDS_P + c4 * 4) = hi;
      *(u16x4*)(Al + r * LDS_P + c4 * 4) = lo;
    }
#pragma unroll
    for (int cc = 0; cc < 2; cc++) {  // B: WxT 128 u'-rows x 64 k copy
      int c = t + cc * 512;
      int r = c >> 3, c8 = c & 7;
      *(u16x8*)(Bh + r * LDS_P + c8 * 8) =
          *(const u16x8*)(Wxth + (size_t)(n_base + r) * 256 + kb + c8 * 8);
      *(u16x8*)(Bl + r * LDS_P + c8 * 8) =
          *(const u16x8*)(Wxtl + (size_t)(n_base + r) * 256 + kb + c8 * 8);
    }
    __syncthreads();
#pragma unroll
    for (int kk = 0; kk < 64; kk += 32) {
      bf16x8 ah = __builtin_bit_cast(bf16x8, *(const u16x8*)(Ah + (msub * 16 + l16) * LDS_P + kk + quad * 8));
      bf16x8 al = __builtin_bit_cast(bf16x8, *(const u16x8*)(Al + (msub * 16 + l16) * LDS_P + kk + quad * 8));
#pragma unroll
      for (int tN = 0; tN < 4; tN++) {
        int brow = nsub * 64 + tN * 16 + l16;
        bf16x8 bh = __builtin_bit_cast(bf16x8, *(const u16x8*)(Bh + brow * LDS_P + kk + quad * 8));
        bf16x8 bl = __builtin_bit_cast(bf16x8, *(const u16x8*)(Bl + brow * LDS_P + kk + quad * 8));
        acc[tN] = __builtin_amdgcn_mfma_f32_16x16x32_bf16(ah, bh, acc[tN], 0, 0, 0);
        acc[tN] = __builtin_amdgcn_mfma_f32_16x16x32_bf16(ah, bl, acc[tN], 0, 0, 0);
        acc[tN] = __builtin_amdgcn_mfma_f32_16x16x32_bf16(al, bh, acc[tN], 0, 0, 0);
      }
    }
    __syncthreads();
  }
  const int rbase = r0 + msub * 16 + quad * 4;  // b*1024 + m
  const int bI = rbase >> 10;
#pragma unroll
  for (int tN = 0; tN < 4; tN++) {
    int u = n_base + nsub * 64 + tN * 16 + l16;
    float bu = bias[u];
#pragma unroll
    for (int i = 0; i < 4; i++) {
      int mI = (rbase + i) & 1023;
      Xpre[((size_t)mI * 8 + bI) * 256 + u] = acc[tN][i] + bu;
    }
  }
}

// ---------------- K4: sequential scan — R15 VERBATIM (622us proven) ---------
// 8 WGs (1 batch each), 8 waves. Wave w owns cols [w*32,w*32+32) = 2
// n-tiles. A-tile: 2 rows (h hi/lo), read row clamped to l16&1 ->
// broadcast, conflict-free. Quads 0/1 both hold valid (hi,lo) in C regs
// [0],[1]; quad0 -> tile0, quad1 -> tile1 -> 1 tanh chain/lane. MFMA
// interleave keeps 4 independent accumulator chains (a0a,a1a,a0b,a1b) —
// REQUIRED (R17: 2 chains exposed MFMA latency, +35%). All 8 ds_reads
// hoisted to step top. Nothing precedes MFMA issue (R16 lesson).
__global__ __launch_bounds__(512, 2) void rnn_scan(const u16* __restrict__ Whth,
                                                   const u16* __restrict__ Whtl,
                                                   const float* __restrict__ Xpre,
                                                   float* __restrict__ out) {
  __shared__ u16 h2[2][2 * HP_B];
  const int b = blockIdx.x;
  const int t = threadIdx.x;
  const int w = t >> 6, lane = t & 63, quad = lane >> 4, l16 = lane & 15;
  const int colbase = w * 32;
  const bool epi = (quad < 2);           // quad0 -> tile0, quad1 -> tile1
  const int col_e = colbase + quad * 16 + l16;  // valid for epi lanes

  // Preload Wh hi+lo fragments: 2 n-tiles x 8 k-blocks, hi+lo
  bf16x8 bwh[2][8], bwl[2][8];
#pragma unroll
  for (int tN = 0; tN < 2; tN++) {
    const u16* wph = Whth + (size_t)(colbase + tN * 16 + l16) * 256 + quad * 8;
    const u16* wpl = Whtl + (size_t)(colbase + tN * 16 + l16) * 256 + quad * 8;
#pragma unroll
    for (int kb = 0; kb < 8; kb++) {
      bwh[tN][kb] = __builtin_bit_cast(bf16x8, *(const u16x8*)(wph + kb * 32));
      bwl[tN][kb] = __builtin_bit_cast(bf16x8, *(const u16x8*)(wpl + kb * 32));
    }
  }
  for (int i = t; i < 2 * 2 * HP_B; i += 512) ((u16*)h2)[i] = 0;

  // c banks 0..3: additive input for steps m4+0..m4+3 (epi lanes only).
  float cb[4];
  if (epi) {
#pragma unroll
    for (int k = 0; k < 4; k++) cb[k] = Xpre[(size_t)k * 2048 + b * 256 + col_e];
  }
  // Running pointers (advance by constants; no per-step re-derivation).
  const float* ldp = Xpre + 4 * 2048 + b * 256 + col_e;
  float* outp = out + (size_t)b * 262144 + col_e;
  // Hoisted LDS bases. Read base: row clamped to l16&1 (broadcast dup rows).
  const u16* rb0 = &h2[0][(l16 & 1) * HP_B + quad * 8];
  const u16* rb1 = &h2[1][(l16 & 1) * HP_B + quad * 8];
  u16* wb0 = &h2[0][0];
  u16* wb1 = &h2[1][0];
  __syncthreads();

  for (int m4 = 0; m4 < 1024; m4 += 4) {
#pragma unroll
    for (int k = 0; k < 4; k++) {
      const int p = k & 1;                       // compile-time in unrolled body
      const u16* rb = p ? rb1 : rb0;
      u16* hw = p ? wb0 : wb1;                   // write the other buffer

      // Hoist all 8 A-fragment reads (one lgkmcnt ramp, MFMAs pipeline).
      bf16x8 af[8];
#pragma unroll
      for (int kb = 0; kb < 8; kb++)
        af[kb] = __builtin_bit_cast(bf16x8, *(const u16x8*)(rb + kb * 32));

      f32x4 a0a = {0.f,0.f,0.f,0.f}, a0b = {0.f,0.f,0.f,0.f};
      f32x4 a1a = {0.f,0.f,0.f,0.f}, a1b = {0.f,0.f,0.f,0.f};
#pragma unroll
      for (int kb = 0; kb < 4; kb++) {
        a0a = __builtin_amdgcn_mfma_f32_16x16x32_bf16(af[kb], bwh[0][kb], a0a, 0, 0, 0);
        a1a = __builtin_amdgcn_mfma_f32_16x16x32_bf16(af[kb], bwh[1][kb], a1a, 0, 0, 0);
        a0b = __builtin_amdgcn_mfma_f32_16x16x32_bf16(af[kb + 4], bwh[0][kb + 4], a0b, 0, 0, 0);
        a1b = __builtin_amdgcn_mfma_f32_16x16x32_bf16(af[kb + 4], bwh[1][kb + 4], a1b, 0, 0, 0);
        a0a = __builtin_amdgcn_mfma_f32_16x16x32_bf16(af[kb], bwl[0][kb], a0a, 0, 0, 0);
        a1a = __builtin_amdgcn_mfma_f32_16x16x32_bf16(af[kb], bwl[1][kb], a1a, 0, 0, 0);
        a0b = __builtin_amdgcn_mfma_f32_16x16x32_bf16(af[kb + 4], bwl[0][kb + 4], a0b, 0, 0, 0);
        a1b = __builtin_amdgcn_mfma_f32_16x16x32_bf16(af[kb + 4], bwl[1][kb + 4], a1b, 0, 0, 0);
      }

      // Epilogue distributed: quad0 uses (a0a,a0b), quad1 uses (a1a,a1b).
      if (epi) {
        float sA0 = quad ? a1a[0] : a0a[0];
        float sA1 = quad ? a1a[1] : a0a[1];
        float sB0 = quad ? a1b[0] : a0b[0];
        float sB1 = quad ? a1b[1] : a0b[1];
        float hi_part = sA0 + sB0;
        float lo_part = sA1 + sB1;
        float x = (hi_part + lo_part) + cb[k];
        float y = tanh_fast(x);
        HiLo s = splitf(y);
        hw[col_e] = s.hi;           // row 0 = h_hi
        hw[HP_B + col_e] = s.lo;    // row 1 = h_lo
        *outp = y;                  // fire-and-forget (vmcnt never drained)
        // Prefetch c for step m+4 into the bank just consumed.
        if (m4 <= 1019 - k) {
          cb[k] = *ldp;
          ldp += 2048;
        }
      }
      outp += 256;
      sync_lds_only();
    }
  }
}

extern "C" void kernel_launch(void* const* d_in, const int* in_sizes, int n_in,
                              void* d_out, int out_size, void* d_ws, size_t ws_size,
                              hipStream_t stream) {
  (void)in_sizes; (void)n_in; (void)out_size; (void)ws_size;
  const float* seq   = (const float*)d_in[0];  // (8,1024,256) f32
  const float* graph = (const float*)d_in[1];  // (8,1024,1024) f32
  const float* E     = (const float*)d_in[2];  // (256,256) f32
  const float* Wx    = (const float*)d_in[3];  // (256,256) f32
  const float* Wh    = (const float*)d_in[4];  // (256,256) f32
  const float* bias  = (const float*)d_in[5];  // (256,) f32
  float* out = (float*)d_out;                  // (8,1024,256) f32

  // workspace layout (bytes): ~26 MB total
  char* w = (char*)d_ws;
  float* rnorm  = (float*)(w + 0);          //  32 KB
  u16*   Wxth   = (u16*)(w + 294912);       // 128 KB each
  u16*   Wxtl   = (u16*)(w + 425984);
  u16*   Whth   = (u16*)(w + 557056);
  u16*   Whtl   = (u16*)(w + 688128);
  u16*   betaTh = (u16*)(w + 819200);       // 4 MB [b][u][l] (raw, no rnorm)
  u16*   betaTl = (u16*)(w + 5013504);      // 4 MB
  float* agg    = (float*)(w + 9207808);    // 8 MB [b][m][u]
  float* Xpre   = (float*)(w + 17596416);   // 8 MB [m][b][u]

  front1<<<1536, 512, 0, stream>>>(Wx, Wxth, Wxtl, Wh, Whth, Whtl,
                                   graph, rnorm, seq, E, betaTh, betaTl);
  gemm_agg<<<dim3(16, 2, 8), 512, 0, stream>>>(graph, betaTh, betaTl, rnorm, agg);
  gemm_xpre<<<dim3(128, 2), 512, 0, stream>>>(agg, Wxth, Wxtl, bias, Xpre);
  rnn_scan<<<dim3(8), 512, 0, stream>>>(Whth, Whtl, Xpre, out);
}